// Round 10
// baseline (324.450 us; speedup 1.0000x reference)
//
#include <hip/hip_runtime.h>
#include <stdint.h>

// SAGE_876173328847: 2-layer bipartite SAGEConv (mean agg) + log_softmax.
// N0=200000, N1=100000, N2=20000, E1=1.6M, E2=320K, D_IN=128, D_H=256, D_OUT=64.
//
// R1: atomic scatter -> CSR build + gather (3309 -> 667 us).
// R2/R3: bf16 heavy path + MFMA GEMMs (667 -> 547 us).
// R4: fused mega-kernel, h1 lives only in LDS (547 -> 472 us).
// R7: scan-based multi-split CSR build, zero global atomics (-> 366 us).
// R8: spill-free mega (366 -> 347 us). R9: launch fusion 22->14 (-> 285 us).
// R10: mega was barrier-chain-bound (12 staging rounds x 2 barriers for 80cyc
//      of MFMA each; prefetch didn't help). Rewrite: per-WAVE 16-row tiles,
//      A and B loaded global->fragment-layout directly (fully coalesced lines;
//      W is L2-resident), h1 transposed through a per-wave-private LDS slice.
//      1 barrier total, LDS 76->33 KB.

#define CN0 200000
#define CN1 100000
#define CN2 20000
#define CE1 1600000
#define CE2 320000
#define CD_IN 128
#define CD_H 256
#define CD_OUT 64

// multi-split geometry: bucket = dst >> 9 (512 dsts per bucket)
#define NBK1 196          // ceil(N1/512)
#define NBK2 40           // ceil(N2/512)
#define G1 256
#define G2 64
#define CHUNK1 6250       // E1 / G1
#define CHUNK2 5000       // E2 / G2

typedef __bf16 bf16x8 __attribute__((ext_vector_type(8)));
typedef float f32x4 __attribute__((ext_vector_type(4)));
typedef uint16_t u16x4 __attribute__((ext_vector_type(4)));

__device__ inline uint16_t f2bf(float f) {
  uint32_t u = __float_as_uint(f);
  return (uint16_t)((u + 0x7fffu + ((u >> 16) & 1u)) >> 16);
}

// ---------------- dtype converts ----------------
__global__ __launch_bounds__(256) void cvt_f32_bf16_v4(
    const float* __restrict__ in, uint16_t* __restrict__ out, int n4) {
  int i = blockIdx.x * 256 + threadIdx.x;
  if (i >= n4) return;
  float4 v = reinterpret_cast<const float4*>(in)[i];
  u16x4 o = {f2bf(v.x), f2bf(v.y), f2bf(v.z), f2bf(v.w)};
  reinterpret_cast<u16x4*>(out)[i] = o;
}

__global__ __launch_bounds__(256) void cvt_weights(
    const float* __restrict__ Wl1, const float* __restrict__ Wr1,
    const float* __restrict__ Wl2, const float* __restrict__ Wr2,
    uint16_t* __restrict__ wcat, uint16_t* __restrict__ w2cat) {
  int i = blockIdx.x * 256 + threadIdx.x;  // 98304 total
  if (i < 65536) {
    int j = i >> 8, k = i & 255;
    float v = (k < 128) ? Wl1[j * 128 + k] : Wr1[j * 128 + (k - 128)];
    wcat[i] = f2bf(v);
  } else {
    int ii = i - 65536;                    // 0..32767
    int r = ii >> 8, k = ii & 255;
    float v = (r < 64) ? Wl2[r * 256 + k] : Wr2[(r - 64) * 256 + k];
    w2cat[ii] = f2bf(v);
  }
}

// ---------------- dual-layer scan-based multi-split ----------------
__global__ __launch_bounds__(256) void csr_count(
    const int* __restrict__ dst1, const int* __restrict__ dst2,
    int* __restrict__ H1, int* __restrict__ H2) {
  __shared__ int hist[256];
  int g = blockIdx.x, t = threadIdx.x;
  const int* dst; int* H; int E, nb, chunk;
  if (g < G1) { dst = dst1; H = H1; E = CE1; nb = NBK1; chunk = CHUNK1; }
  else { g -= G1; dst = dst2; H = H2; E = CE2; nb = NBK2; chunk = CHUNK2; }
  hist[t] = 0;
  __syncthreads();
  int e0 = g * chunk, e1 = min(e0 + chunk, E);
  for (int e = e0 + t; e < e1; e += 256) atomicAdd(&hist[dst[e] >> 9], 1);
  __syncthreads();
  if (t < nb) H[g * nb + t] = hist[t];
}

__global__ __launch_bounds__(256) void csr_scan(
    int* __restrict__ H1, int* __restrict__ H2,
    int* __restrict__ T1, int* __restrict__ T2) {
  __shared__ int sm[256];
  int b = blockIdx.x, t = threadIdx.x;
  int* H; int* T; int nb, G;
  if (b < NBK1) { H = H1; T = T1; nb = NBK1; G = G1; }
  else { b -= NBK1; H = H2; T = T2; nb = NBK2; G = G2; }
  int v = (t < G) ? H[t * nb + b] : 0;
  sm[t] = v;
  __syncthreads();
#pragma unroll
  for (int off = 1; off < 256; off <<= 1) {
    int u = (t >= off) ? sm[t - off] : 0;
    __syncthreads();
    sm[t] += u;
    __syncthreads();
  }
  if (t < G) H[t * nb + b] = sm[t] - v;  // exclusive over chunks
  if (t == 255) T[b] = sm[255];          // bucket total
}

__global__ __launch_bounds__(256) void csr_base(
    const int* __restrict__ T1, const int* __restrict__ T2,
    int* __restrict__ Bb1, int* __restrict__ Bb2) {
  __shared__ int sm[256];
  int t = threadIdx.x;
  const int* T; int* Bb; int nb;
  if (blockIdx.x == 0) { T = T1; Bb = Bb1; nb = NBK1; }
  else { T = T2; Bb = Bb2; nb = NBK2; }
  int v = (t < nb) ? T[t] : 0;
  sm[t] = v;
  __syncthreads();
#pragma unroll
  for (int off = 1; off < 256; off <<= 1) {
    int u = (t >= off) ? sm[t - off] : 0;
    __syncthreads();
    sm[t] += u;
    __syncthreads();
  }
  if (t < nb) Bb[t] = sm[t] - v;
}

__global__ __launch_bounds__(256) void csr_place(
    const int* __restrict__ src1, const int* __restrict__ dst1,
    const int* __restrict__ src2, const int* __restrict__ dst2,
    const int* __restrict__ H1, const int* __restrict__ H2,
    const int* __restrict__ Bb1, const int* __restrict__ Bb2,
    uint32_t* __restrict__ pairs1, uint32_t* __restrict__ pairs2) {
  __shared__ int curs[256];
  int g = blockIdx.x, t = threadIdx.x;
  const int* src; const int* dst; const int* H; const int* Bb;
  uint32_t* pairs; int E, nb, chunk;
  if (g < G1) { src = src1; dst = dst1; H = H1; Bb = Bb1; pairs = pairs1;
                E = CE1; nb = NBK1; chunk = CHUNK1; }
  else { g -= G1; src = src2; dst = dst2; H = H2; Bb = Bb2; pairs = pairs2;
         E = CE2; nb = NBK2; chunk = CHUNK2; }
  if (t < nb) curs[t] = Bb[t] + H[g * nb + t];
  __syncthreads();
  int e0 = g * chunk, e1 = min(e0 + chunk, E);
  for (int e = e0 + t; e < e1; e += 256) {
    int d = dst[e];
    int b = d >> 9;
    int p = atomicAdd(&curs[b], 1);
    pairs[p] = (uint32_t)src[e] | ((uint32_t)(d & 511) << 18);
  }
}

__global__ __launch_bounds__(256) void csr_bdeg(
    const uint32_t* __restrict__ pairs1, const uint32_t* __restrict__ pairs2,
    const int* __restrict__ Bb1, const int* __restrict__ Bb2,
    const int* __restrict__ T1, const int* __restrict__ T2,
    int* __restrict__ deg1, int* __restrict__ deg2) {
  __shared__ int cnt[512];
  int b = blockIdx.x, t = threadIdx.x;
  const uint32_t* pairs; const int* Bb; const int* T; int* deg; int ndst;
  if (b < NBK1) { pairs = pairs1; Bb = Bb1; T = T1; deg = deg1; ndst = CN1; }
  else { b -= NBK1; pairs = pairs2; Bb = Bb2; T = T2; deg = deg2; ndst = CN2; }
  cnt[t] = 0;
  cnt[t + 256] = 0;
  __syncthreads();
  int s0 = Bb[b], n = T[b];
  for (int i = t; i < n; i += 256) atomicAdd(&cnt[pairs[s0 + i] >> 18], 1);
  __syncthreads();
  int d0 = b << 9;
#pragma unroll
  for (int j = 0; j < 2; ++j) {
    int dd = d0 + t + j * 256;
    if (dd < ndst) deg[dd] = cnt[t + j * 256];
  }
}

__global__ __launch_bounds__(256) void csr_scan_local(
    const int* __restrict__ deg1, const int* __restrict__ deg2,
    int* __restrict__ R1, int* __restrict__ R2,
    int* __restrict__ part1, int* __restrict__ part2) {
  __shared__ int sm[256];
  int b = blockIdx.x, t = threadIdx.x;
  const int* deg; int* R; int* part; int N;
  if (b < NBK1) { deg = deg1; R = R1; part = part1; N = CN1; }
  else { b -= NBK1; deg = deg2; R = R2; part = part2; N = CN2; }
  int base = b * 512;
  int i0 = base + 2 * t, i1 = base + 2 * t + 1;
  int a = (i0 < N) ? deg[i0] : 0;
  int bb = (i1 < N) ? deg[i1] : 0;
  int s = a + bb;
  sm[t] = s;
  __syncthreads();
#pragma unroll
  for (int off = 1; off < 256; off <<= 1) {
    int v = (t >= off) ? sm[t - off] : 0;
    __syncthreads();
    sm[t] += v;
    __syncthreads();
  }
  int excl = sm[t] - s;
  if (i0 < N) R[i0] = excl;
  if (i1 < N) R[i1] = excl + a;
  if (t == 255) part[b] = sm[255];
}

__global__ __launch_bounds__(256) void csr_scan_part(
    int* __restrict__ part1, int* __restrict__ part2) {
  __shared__ int sm[256];
  int t = threadIdx.x;
  int* part; int B;
  if (blockIdx.x == 0) { part = part1; B = NBK1; }
  else { part = part2; B = NBK2; }
  int v = (t < B) ? part[t] : 0;
  sm[t] = v;
  __syncthreads();
#pragma unroll
  for (int off = 1; off < 256; off <<= 1) {
    int u = (t >= off) ? sm[t - off] : 0;
    __syncthreads();
    sm[t] += u;
    __syncthreads();
  }
  if (t < B) part[t] = sm[t] - v;
}

// bplace with addback folded in: final offset = R[dd] + part[bucket]
__global__ __launch_bounds__(256) void csr_bplace(
    const uint32_t* __restrict__ pairs1, const uint32_t* __restrict__ pairs2,
    const int* __restrict__ Bb1, const int* __restrict__ Bb2,
    const int* __restrict__ T1, const int* __restrict__ T2,
    const int* __restrict__ R1, const int* __restrict__ R2,
    const int* __restrict__ part1, const int* __restrict__ part2,
    int* __restrict__ esrc1, int* __restrict__ esrc2) {
  __shared__ int curs[512];
  int b = blockIdx.x, t = threadIdx.x;
  const uint32_t* pairs; const int* Bb; const int* T; const int* R;
  const int* part; int* esrc; int ndst;
  if (b < NBK1) { pairs = pairs1; Bb = Bb1; T = T1; R = R1; part = part1;
                  esrc = esrc1; ndst = CN1; }
  else { b -= NBK1; pairs = pairs2; Bb = Bb2; T = T2; R = R2; part = part2;
         esrc = esrc2; ndst = CN2; }
  int d0 = b << 9;
  int pb = part[b];
#pragma unroll
  for (int j = 0; j < 2; ++j) {
    int dd = d0 + t + j * 256;
    curs[t + j * 256] = (dd < ndst) ? R[dd] + pb : 0;
  }
  __syncthreads();
  int s0 = Bb[b], n = T[b];
  for (int i = t; i < n; i += 256) {
    uint32_t pk = pairs[s0 + i];
    int p = atomicAdd(&curs[pk >> 18], 1);
    esrc[p] = (int)(pk & 0x3FFFFu);
  }
}

// ---------------- gather-mean (bf16 in), layer 1: 64 lanes/dst ----------------
__global__ __launch_bounds__(256) void sage_gather1(
    const uint16_t* __restrict__ xbf, const int* __restrict__ esrc,
    const int* __restrict__ R, const int* __restrict__ part,
    const int* __restrict__ deg, uint16_t* __restrict__ agg) {
  int d = blockIdx.x * 4 + (threadIdx.x >> 6);
  int c = threadIdx.x & 63;
  if (d >= CN1) return;
  int start = R[d] + part[d >> 9], n = deg[d];
  const uint32_t* xw = reinterpret_cast<const uint32_t*>(xbf);
  float a0 = 0.f, a1 = 0.f;
  int i = 0;
  for (; i + 4 <= n; i += 4) {
    int s0 = esrc[start + i + 0];
    int s1 = esrc[start + i + 1];
    int s2 = esrc[start + i + 2];
    int s3 = esrc[start + i + 3];
    uint32_t v0 = xw[(size_t)s0 * 64 + c];
    uint32_t v1 = xw[(size_t)s1 * 64 + c];
    uint32_t v2 = xw[(size_t)s2 * 64 + c];
    uint32_t v3 = xw[(size_t)s3 * 64 + c];
    a0 += __uint_as_float(v0 << 16) + __uint_as_float(v1 << 16) +
          __uint_as_float(v2 << 16) + __uint_as_float(v3 << 16);
    a1 += __uint_as_float(v0 & 0xffff0000u) + __uint_as_float(v1 & 0xffff0000u) +
          __uint_as_float(v2 & 0xffff0000u) + __uint_as_float(v3 & 0xffff0000u);
  }
  for (; i < n; ++i) {
    uint32_t v = xw[(size_t)esrc[start + i] * 64 + c];
    a0 += __uint_as_float(v << 16);
    a1 += __uint_as_float(v & 0xffff0000u);
  }
  float inv = 1.0f / fmaxf((float)n, 1.0f);
  a0 *= inv; a1 *= inv;
  uint32_t packed = (uint32_t)f2bf(a0) | ((uint32_t)f2bf(a1) << 16);
  reinterpret_cast<uint32_t*>(agg)[(size_t)d * 64 + c] = packed;
}

// ---------------- gather-mean (bf16 in), layer 2: 32 lanes/dst, f32 out ----
__global__ __launch_bounds__(256) void sage_gather2(
    const uint16_t* __restrict__ t2, const int* __restrict__ esrc,
    const int* __restrict__ R, const int* __restrict__ part,
    const int* __restrict__ deg, float* __restrict__ agg) {
  int d = blockIdx.x * 8 + (threadIdx.x >> 5);
  int c = threadIdx.x & 31;
  if (d >= CN2) return;
  int start = R[d] + part[d >> 9], n = deg[d];
  const uint32_t* tw = reinterpret_cast<const uint32_t*>(t2);
  float a0 = 0.f, a1 = 0.f;
  int i = 0;
  for (; i + 4 <= n; i += 4) {
    int s0 = esrc[start + i + 0];
    int s1 = esrc[start + i + 1];
    int s2 = esrc[start + i + 2];
    int s3 = esrc[start + i + 3];
    uint32_t v0 = tw[(size_t)s0 * 32 + c];
    uint32_t v1 = tw[(size_t)s1 * 32 + c];
    uint32_t v2 = tw[(size_t)s2 * 32 + c];
    uint32_t v3 = tw[(size_t)s3 * 32 + c];
    a0 += __uint_as_float(v0 << 16) + __uint_as_float(v1 << 16) +
          __uint_as_float(v2 << 16) + __uint_as_float(v3 << 16);
    a1 += __uint_as_float(v0 & 0xffff0000u) + __uint_as_float(v1 & 0xffff0000u) +
          __uint_as_float(v2 & 0xffff0000u) + __uint_as_float(v3 & 0xffff0000u);
  }
  for (; i < n; ++i) {
    uint32_t v = tw[(size_t)esrc[start + i] * 32 + c];
    a0 += __uint_as_float(v << 16);
    a1 += __uint_as_float(v & 0xffff0000u);
  }
  float inv = 1.0f / fmaxf((float)n, 1.0f);
  float2 o = {a0 * inv, a1 * inv};
  reinterpret_cast<float2*>(agg)[(size_t)d * 32 + c] = o;
}

// ---------------- MEGA kernel (R10: per-wave tiles, no staging) ----------------
// Each wave owns 16 rows. A- and B-fragments load DIRECTLY from global in MFMA
// fragment layout (fully coalesced 64B lines; wcat/w2cat are L2-resident).
// h1 (C layout) is transposed to A-frag layout through a per-wave-private LDS
// slice; phase-2 results staged in the same slice, then coalesced int4 stores.
__global__ __launch_bounds__(256, 3) void sage_mega(
    const uint16_t* __restrict__ agg, const uint16_t* __restrict__ xbf,
    const uint16_t* __restrict__ wcat, const uint16_t* __restrict__ w2cat,
    const float* __restrict__ bias, uint16_t* __restrict__ t2,
    float* __restrict__ outp) {
  __shared__ uint16_t h1s[4 * 16 * 264];  // 33792 B; per-wave 16x264 slice
  const int tid = threadIdx.x;
  const int w = tid >> 6;
  const int lane = tid & 63;
  const int lr = lane >> 4;   // k-group (frags) / row-group (C)
  const int lc = lane & 15;   // A-row / B-col / C-col
  const int row0 = blockIdx.x * 64 + w * 16;   // wave's first row
  uint16_t* hw = &h1s[w * (16 * 264)];

  // A fragments: 16 rows x K=256 from [agg | x], frag layout row=lc, k=lr*8+t*32
  int arow = row0 + lc;
  arow = arow < CN1 ? arow : CN1 - 1;
  bf16x8 afr[8];
#pragma unroll
  for (int t = 0; t < 8; ++t) {
    const uint16_t* Asrc = (t < 4) ? agg : xbf;
    const int koff = (t < 4) ? t * 32 : t * 32 - 128;
    afr[t] = *reinterpret_cast<const bf16x8*>(
        Asrc + (size_t)arow * CD_IN + koff + lr * 8);
  }
  float bv[16];
#pragma unroll
  for (int n = 0; n < 16; ++n) bv[n] = bias[n * 16 + lc];

  // ---- phase 1: h1(16x256) = relu(A @ Wcat^T + b) -> LDS (C->A transpose) ----
#pragma unroll 2
  for (int n = 0; n < 16; ++n) {
    bf16x8 bfr[8];
#pragma unroll
    for (int t = 0; t < 8; ++t)
      bfr[t] = *reinterpret_cast<const bf16x8*>(
          wcat + (size_t)(n * 16 + lc) * 256 + t * 32 + lr * 8);
    f32x4 acc = (f32x4)0.0f;
#pragma unroll
    for (int t = 0; t < 8; ++t)
      acc = __builtin_amdgcn_mfma_f32_16x16x32_bf16(afr[t], bfr[t], acc, 0, 0, 0);
#pragma unroll
    for (int i = 0; i < 4; ++i) {
      float v = fmaxf(acc[i] + bv[n], 0.0f);
      hw[(lr * 4 + i) * 264 + n * 16 + lc] = f2bf(v);  // row=(lane>>4)*4+i, col
    }
  }

  // ---- phase 2 A-fragments from LDS: row=lc, k=lr*8+t*32 ----
  bf16x8 a2[8];
#pragma unroll
  for (int t = 0; t < 8; ++t)
    a2[t] = *reinterpret_cast<const bf16x8*>(&hw[lc * 264 + t * 32 + lr * 8]);
  __syncthreads();  // a2 reads complete before slice is reused for staging

  uint16_t* t2s = hw;                  // [16][64] u16 (2 KB)
  float* outs = (float*)(hw + 1024);   // [16][64] f32 (4 KB)
  const bool do_out = (row0 < CN2);    // CN2 % 16 == 0 -> whole wave in/out
  const int n2max = do_out ? 8 : 4;
#pragma unroll 2
  for (int n2 = 0; n2 < n2max; ++n2) {
    bf16x8 b2[8];
#pragma unroll
    for (int t = 0; t < 8; ++t)
      b2[t] = *reinterpret_cast<const bf16x8*>(
          w2cat + (size_t)(n2 * 16 + lc) * 256 + t * 32 + lr * 8);
    f32x4 acc = (f32x4)0.0f;
#pragma unroll
    for (int t = 0; t < 8; ++t)
      acc = __builtin_amdgcn_mfma_f32_16x16x32_bf16(a2[t], b2[t], acc, 0, 0, 0);
    if (n2 < 4) {
#pragma unroll
      for (int i = 0; i < 4; ++i)
        t2s[(lr * 4 + i) * 64 + n2 * 16 + lc] = f2bf(acc[i]);
    } else {
#pragma unroll
      for (int i = 0; i < 4; ++i)
        outs[(lr * 4 + i) * 64 + (n2 - 4) * 16 + lc] = acc[i];
    }
  }

  // ---- per-wave coalesced stores (same-wave LDS ordering via lgkmcnt) ----
#pragma unroll
  for (int i = 0; i < 2; ++i) {
    int q = lane + 64 * i;             // 0..127
    int r = q >> 3, c = q & 7;
    int rg = row0 + r;
    if (rg < CN1)
      reinterpret_cast<int4*>(t2 + (size_t)rg * 64)[c] =
          *reinterpret_cast<const int4*>(&t2s[r * 64 + c * 8]);
  }
  if (do_out) {
#pragma unroll
    for (int i = 0; i < 4; ++i) {
      int q = lane + 64 * i;           // 0..255
      int r = q >> 4, c = q & 15;
      int rg = row0 + r;
      reinterpret_cast<int4*>(outp + (size_t)rg * 64)[c] =
          *reinterpret_cast<const int4*>(&outs[r * 64 + c * 4]);
    }
  }
}

// ---------------- finalize: out = log_softmax(out + agg2 + b2) ----------------
__global__ __launch_bounds__(256) void sage_finalize(
    const float* __restrict__ agg2, const float* __restrict__ b,
    float* __restrict__ out) {
  int row = blockIdx.x * 4 + (threadIdx.x >> 6);
  int lane = threadIdx.x & 63;
  if (row >= CN2) return;
  size_t o = (size_t)row * CD_OUT + lane;
  float v = out[o] + agg2[o] + b[lane];
  float m = v;
#pragma unroll
  for (int d = 32; d > 0; d >>= 1) m = fmaxf(m, __shfl_xor(m, d));
  float e = expf(v - m);
  float s = e;
#pragma unroll
  for (int d = 32; d > 0; d >>= 1) s += __shfl_xor(s, d);
  out[o] = v - m - logf(s);
}

extern "C" void kernel_launch(void* const* d_in, const int* in_sizes, int n_in,
                              void* d_out, int out_size, void* d_ws, size_t ws_size,
                              hipStream_t stream) {
  const float* x    = (const float*)d_in[0];
  const int* src1   = (const int*)d_in[1];
  const int* dst1   = (const int*)d_in[2];
  const int* src2   = (const int*)d_in[3];
  const int* dst2   = (const int*)d_in[4];
  const float* W_l1 = (const float*)d_in[5];
  const float* b_l1 = (const float*)d_in[6];
  const float* W_r1 = (const float*)d_in[7];
  const float* W_l2 = (const float*)d_in[8];
  const float* b_l2 = (const float*)d_in[9];
  const float* W_r2 = (const float*)d_in[10];
  float* out = (float*)d_out;
  char* base = (char*)d_ws;

  // ---- workspace layout (bytes), ~111.5 MB ----
  uint16_t* x_bf  = (uint16_t*)base;                       // 51.2 MB
  uint16_t* t2_bf = (uint16_t*)(base + 51200000);          // 12.8 MB
  uint32_t* pairs1= (uint32_t*)(base + 64000000);          // 6.4 MB (E1*4)
  uint32_t* pairs2= (uint32_t*)(base + 70400000);          // 1.28 MB (E2*4)
  uint16_t* agg_bf= (uint16_t*)(base + 71680000);          // 25.6 MB
  float* agg2     = (float*)(base + 97280000);             // 5.12 MB
  int* deg1 = (int*)(base + 102400000);                    // 400 KB
  int* R1   = (int*)(base + 102800000);                    // 400 KB
  int* esrc1= (int*)(base + 103200000);                    // 6.4 MB
  int* deg2 = (int*)(base + 109600000);                    // 80 KB
  int* R2   = (int*)(base + 109680000);                    // 80 KB
  int* esrc2= (int*)(base + 109760000);                    // 1.28 MB
  int* H1   = (int*)(base + 111040000);                    // 200,704 B
  int* H2   = (int*)(base + 111240704);                    // 10,240 B
  char* misc = base + 111250944;
  int* T1  = (int*)(misc);
  int* Bb1 = (int*)(misc + 1024);
  int* T2  = (int*)(misc + 2048);
  int* Bb2 = (int*)(misc + 3072);
  int* part1 = (int*)(misc + 4096);
  int* part2 = (int*)(misc + 5120);
  uint16_t* wcat  = (uint16_t*)(misc + 6144);              // 128 KB
  uint16_t* w2cat = wcat + 65536;                          // 64 KB

  if (ws_size < 112000000u) return;

  // ---- converts ----
  cvt_f32_bf16_v4<<<(CN0 * CD_IN / 4 + 255) / 256, 256, 0, stream>>>(x, x_bf, CN0 * CD_IN / 4);
  cvt_weights<<<384, 256, 0, stream>>>(W_l1, W_r1, W_l2, W_r2, wcat, w2cat);

  // ---- dual-layer CSR build ----
  csr_count<<<G1 + G2, 256, 0, stream>>>(dst1, dst2, H1, H2);
  csr_scan<<<NBK1 + NBK2, 256, 0, stream>>>(H1, H2, T1, T2);
  csr_base<<<2, 256, 0, stream>>>(T1, T2, Bb1, Bb2);
  csr_place<<<G1 + G2, 256, 0, stream>>>(src1, dst1, src2, dst2, H1, H2,
                                         Bb1, Bb2, pairs1, pairs2);
  csr_bdeg<<<NBK1 + NBK2, 256, 0, stream>>>(pairs1, pairs2, Bb1, Bb2, T1, T2,
                                            deg1, deg2);
  csr_scan_local<<<NBK1 + NBK2, 256, 0, stream>>>(deg1, deg2, R1, R2, part1, part2);
  csr_scan_part<<<2, 256, 0, stream>>>(part1, part2);
  csr_bplace<<<NBK1 + NBK2, 256, 0, stream>>>(pairs1, pairs2, Bb1, Bb2, T1, T2,
                                              R1, R2, part1, part2, esrc1, esrc2);

  // ---- gather1 -> mega -> gather2 -> finalize ----
  sage_gather1<<<(CN1 + 3) / 4, 256, 0, stream>>>(x_bf, esrc1, R1, part1, deg1, agg_bf);
  sage_mega<<<(CN1 + 63) / 64, 256, 0, stream>>>(
      agg_bf, x_bf, wcat, w2cat, b_l1, t2_bf, out);
  sage_gather2<<<(CN2 + 7) / 8, 256, 0, stream>>>(t2_bf, esrc2, R2, part2, deg2, agg2);
  sage_finalize<<<(CN2 + 3) / 4, 256, 0, stream>>>(agg2, b_l2, out);
}

// Round 11
// 263.782 us; speedup vs baseline: 1.2300x; 1.2300x over previous
//
#include <hip/hip_runtime.h>
#include <stdint.h>

// SAGE_876173328847: 2-layer bipartite SAGEConv (mean agg) + log_softmax.
// N0=200000, N1=100000, N2=20000, E1=1.6M, E2=320K, D_IN=128, D_H=256, D_OUT=64.
//
// R1: atomic scatter -> CSR build + gather (3309 -> 667 us).
// R2/R3: bf16 heavy path + MFMA GEMMs (667 -> 547 us).
// R4: fused mega-kernel, h1 lives only in LDS (547 -> 472 us).
// R7: scan-based multi-split CSR build, zero global atomics (-> 366 us).
// R8: spill-free mega (-> 347). R9: launch fusion 22->14 (-> 285).
// R10: per-wave 16-row tiles regressed (140 us: L2-latency bound, B reuse=16).
// R11: 32x32x16 MFMA, 32 rows/wave (2x B reuse, half the waves), phase 2 fused
//      into the n-loop via per-wave 2.5 KB LDS transpose tile. Zero barriers.

#define CN0 200000
#define CN1 100000
#define CN2 20000
#define CE1 1600000
#define CE2 320000
#define CD_IN 128
#define CD_H 256
#define CD_OUT 64

// multi-split geometry: bucket = dst >> 9 (512 dsts per bucket)
#define NBK1 196          // ceil(N1/512)
#define NBK2 40           // ceil(N2/512)
#define G1 256
#define G2 64
#define CHUNK1 6250       // E1 / G1
#define CHUNK2 5000       // E2 / G2

typedef __bf16 bf16x8 __attribute__((ext_vector_type(8)));
typedef float f32x4 __attribute__((ext_vector_type(4)));
typedef float f32x16 __attribute__((ext_vector_type(16)));
typedef uint16_t u16x4 __attribute__((ext_vector_type(4)));

__device__ inline uint16_t f2bf(float f) {
  uint32_t u = __float_as_uint(f);
  return (uint16_t)((u + 0x7fffu + ((u >> 16) & 1u)) >> 16);
}

// ---------------- dtype converts ----------------
__global__ __launch_bounds__(256) void cvt_f32_bf16_v4(
    const float* __restrict__ in, uint16_t* __restrict__ out, int n4) {
  int i = blockIdx.x * 256 + threadIdx.x;
  if (i >= n4) return;
  float4 v = reinterpret_cast<const float4*>(in)[i];
  u16x4 o = {f2bf(v.x), f2bf(v.y), f2bf(v.z), f2bf(v.w)};
  reinterpret_cast<u16x4*>(out)[i] = o;
}

__global__ __launch_bounds__(256) void cvt_weights(
    const float* __restrict__ Wl1, const float* __restrict__ Wr1,
    const float* __restrict__ Wl2, const float* __restrict__ Wr2,
    uint16_t* __restrict__ wcat, uint16_t* __restrict__ w2cat) {
  int i = blockIdx.x * 256 + threadIdx.x;  // 98304 total
  if (i < 65536) {
    int j = i >> 8, k = i & 255;
    float v = (k < 128) ? Wl1[j * 128 + k] : Wr1[j * 128 + (k - 128)];
    wcat[i] = f2bf(v);
  } else {
    int ii = i - 65536;                    // 0..32767
    int r = ii >> 8, k = ii & 255;
    float v = (r < 64) ? Wl2[r * 256 + k] : Wr2[(r - 64) * 256 + k];
    w2cat[ii] = f2bf(v);
  }
}

// ---------------- dual-layer scan-based multi-split ----------------
__global__ __launch_bounds__(256) void csr_count(
    const int* __restrict__ dst1, const int* __restrict__ dst2,
    int* __restrict__ H1, int* __restrict__ H2) {
  __shared__ int hist[256];
  int g = blockIdx.x, t = threadIdx.x;
  const int* dst; int* H; int E, nb, chunk;
  if (g < G1) { dst = dst1; H = H1; E = CE1; nb = NBK1; chunk = CHUNK1; }
  else { g -= G1; dst = dst2; H = H2; E = CE2; nb = NBK2; chunk = CHUNK2; }
  hist[t] = 0;
  __syncthreads();
  int e0 = g * chunk, e1 = min(e0 + chunk, E);
  for (int e = e0 + t; e < e1; e += 256) atomicAdd(&hist[dst[e] >> 9], 1);
  __syncthreads();
  if (t < nb) H[g * nb + t] = hist[t];
}

__global__ __launch_bounds__(256) void csr_scan(
    int* __restrict__ H1, int* __restrict__ H2,
    int* __restrict__ T1, int* __restrict__ T2) {
  __shared__ int sm[256];
  int b = blockIdx.x, t = threadIdx.x;
  int* H; int* T; int nb, G;
  if (b < NBK1) { H = H1; T = T1; nb = NBK1; G = G1; }
  else { b -= NBK1; H = H2; T = T2; nb = NBK2; G = G2; }
  int v = (t < G) ? H[t * nb + b] : 0;
  sm[t] = v;
  __syncthreads();
#pragma unroll
  for (int off = 1; off < 256; off <<= 1) {
    int u = (t >= off) ? sm[t - off] : 0;
    __syncthreads();
    sm[t] += u;
    __syncthreads();
  }
  if (t < G) H[t * nb + b] = sm[t] - v;  // exclusive over chunks
  if (t == 255) T[b] = sm[255];          // bucket total
}

__global__ __launch_bounds__(256) void csr_base(
    const int* __restrict__ T1, const int* __restrict__ T2,
    int* __restrict__ Bb1, int* __restrict__ Bb2) {
  __shared__ int sm[256];
  int t = threadIdx.x;
  const int* T; int* Bb; int nb;
  if (blockIdx.x == 0) { T = T1; Bb = Bb1; nb = NBK1; }
  else { T = T2; Bb = Bb2; nb = NBK2; }
  int v = (t < nb) ? T[t] : 0;
  sm[t] = v;
  __syncthreads();
#pragma unroll
  for (int off = 1; off < 256; off <<= 1) {
    int u = (t >= off) ? sm[t - off] : 0;
    __syncthreads();
    sm[t] += u;
    __syncthreads();
  }
  if (t < nb) Bb[t] = sm[t] - v;
}

__global__ __launch_bounds__(256) void csr_place(
    const int* __restrict__ src1, const int* __restrict__ dst1,
    const int* __restrict__ src2, const int* __restrict__ dst2,
    const int* __restrict__ H1, const int* __restrict__ H2,
    const int* __restrict__ Bb1, const int* __restrict__ Bb2,
    uint32_t* __restrict__ pairs1, uint32_t* __restrict__ pairs2) {
  __shared__ int curs[256];
  int g = blockIdx.x, t = threadIdx.x;
  const int* src; const int* dst; const int* H; const int* Bb;
  uint32_t* pairs; int E, nb, chunk;
  if (g < G1) { src = src1; dst = dst1; H = H1; Bb = Bb1; pairs = pairs1;
                E = CE1; nb = NBK1; chunk = CHUNK1; }
  else { g -= G1; src = src2; dst = dst2; H = H2; Bb = Bb2; pairs = pairs2;
         E = CE2; nb = NBK2; chunk = CHUNK2; }
  if (t < nb) curs[t] = Bb[t] + H[g * nb + t];
  __syncthreads();
  int e0 = g * chunk, e1 = min(e0 + chunk, E);
  for (int e = e0 + t; e < e1; e += 256) {
    int d = dst[e];
    int b = d >> 9;
    int p = atomicAdd(&curs[b], 1);
    pairs[p] = (uint32_t)src[e] | ((uint32_t)(d & 511) << 18);
  }
}

__global__ __launch_bounds__(256) void csr_bdeg(
    const uint32_t* __restrict__ pairs1, const uint32_t* __restrict__ pairs2,
    const int* __restrict__ Bb1, const int* __restrict__ Bb2,
    const int* __restrict__ T1, const int* __restrict__ T2,
    int* __restrict__ deg1, int* __restrict__ deg2) {
  __shared__ int cnt[512];
  int b = blockIdx.x, t = threadIdx.x;
  const uint32_t* pairs; const int* Bb; const int* T; int* deg; int ndst;
  if (b < NBK1) { pairs = pairs1; Bb = Bb1; T = T1; deg = deg1; ndst = CN1; }
  else { b -= NBK1; pairs = pairs2; Bb = Bb2; T = T2; deg = deg2; ndst = CN2; }
  cnt[t] = 0;
  cnt[t + 256] = 0;
  __syncthreads();
  int s0 = Bb[b], n = T[b];
  for (int i = t; i < n; i += 256) atomicAdd(&cnt[pairs[s0 + i] >> 18], 1);
  __syncthreads();
  int d0 = b << 9;
#pragma unroll
  for (int j = 0; j < 2; ++j) {
    int dd = d0 + t + j * 256;
    if (dd < ndst) deg[dd] = cnt[t + j * 256];
  }
}

__global__ __launch_bounds__(256) void csr_scan_local(
    const int* __restrict__ deg1, const int* __restrict__ deg2,
    int* __restrict__ R1, int* __restrict__ R2,
    int* __restrict__ part1, int* __restrict__ part2) {
  __shared__ int sm[256];
  int b = blockIdx.x, t = threadIdx.x;
  const int* deg; int* R; int* part; int N;
  if (b < NBK1) { deg = deg1; R = R1; part = part1; N = CN1; }
  else { b -= NBK1; deg = deg2; R = R2; part = part2; N = CN2; }
  int base = b * 512;
  int i0 = base + 2 * t, i1 = base + 2 * t + 1;
  int a = (i0 < N) ? deg[i0] : 0;
  int bb = (i1 < N) ? deg[i1] : 0;
  int s = a + bb;
  sm[t] = s;
  __syncthreads();
#pragma unroll
  for (int off = 1; off < 256; off <<= 1) {
    int v = (t >= off) ? sm[t - off] : 0;
    __syncthreads();
    sm[t] += v;
    __syncthreads();
  }
  int excl = sm[t] - s;
  if (i0 < N) R[i0] = excl;
  if (i1 < N) R[i1] = excl + a;
  if (t == 255) part[b] = sm[255];
}

__global__ __launch_bounds__(256) void csr_scan_part(
    int* __restrict__ part1, int* __restrict__ part2) {
  __shared__ int sm[256];
  int t = threadIdx.x;
  int* part; int B;
  if (blockIdx.x == 0) { part = part1; B = NBK1; }
  else { part = part2; B = NBK2; }
  int v = (t < B) ? part[t] : 0;
  sm[t] = v;
  __syncthreads();
#pragma unroll
  for (int off = 1; off < 256; off <<= 1) {
    int u = (t >= off) ? sm[t - off] : 0;
    __syncthreads();
    sm[t] += u;
    __syncthreads();
  }
  if (t < B) part[t] = sm[t] - v;
}

// bplace with addback folded in: final offset = R[dd] + part[bucket]
__global__ __launch_bounds__(256) void csr_bplace(
    const uint32_t* __restrict__ pairs1, const uint32_t* __restrict__ pairs2,
    const int* __restrict__ Bb1, const int* __restrict__ Bb2,
    const int* __restrict__ T1, const int* __restrict__ T2,
    const int* __restrict__ R1, const int* __restrict__ R2,
    const int* __restrict__ part1, const int* __restrict__ part2,
    int* __restrict__ esrc1, int* __restrict__ esrc2) {
  __shared__ int curs[512];
  int b = blockIdx.x, t = threadIdx.x;
  const uint32_t* pairs; const int* Bb; const int* T; const int* R;
  const int* part; int* esrc; int ndst;
  if (b < NBK1) { pairs = pairs1; Bb = Bb1; T = T1; R = R1; part = part1;
                  esrc = esrc1; ndst = CN1; }
  else { b -= NBK1; pairs = pairs2; Bb = Bb2; T = T2; R = R2; part = part2;
         esrc = esrc2; ndst = CN2; }
  int d0 = b << 9;
  int pb = part[b];
#pragma unroll
  for (int j = 0; j < 2; ++j) {
    int dd = d0 + t + j * 256;
    curs[t + j * 256] = (dd < ndst) ? R[dd] + pb : 0;
  }
  __syncthreads();
  int s0 = Bb[b], n = T[b];
  for (int i = t; i < n; i += 256) {
    uint32_t pk = pairs[s0 + i];
    int p = atomicAdd(&curs[pk >> 18], 1);
    esrc[p] = (int)(pk & 0x3FFFFu);
  }
}

// ---------------- gather-mean (bf16 in), layer 1: 64 lanes/dst ----------------
__global__ __launch_bounds__(256) void sage_gather1(
    const uint16_t* __restrict__ xbf, const int* __restrict__ esrc,
    const int* __restrict__ R, const int* __restrict__ part,
    const int* __restrict__ deg, uint16_t* __restrict__ agg) {
  int d = blockIdx.x * 4 + (threadIdx.x >> 6);
  int c = threadIdx.x & 63;
  if (d >= CN1) return;
  int start = R[d] + part[d >> 9], n = deg[d];
  const uint32_t* xw = reinterpret_cast<const uint32_t*>(xbf);
  float a0 = 0.f, a1 = 0.f;
  int i = 0;
  for (; i + 4 <= n; i += 4) {
    int s0 = esrc[start + i + 0];
    int s1 = esrc[start + i + 1];
    int s2 = esrc[start + i + 2];
    int s3 = esrc[start + i + 3];
    uint32_t v0 = xw[(size_t)s0 * 64 + c];
    uint32_t v1 = xw[(size_t)s1 * 64 + c];
    uint32_t v2 = xw[(size_t)s2 * 64 + c];
    uint32_t v3 = xw[(size_t)s3 * 64 + c];
    a0 += __uint_as_float(v0 << 16) + __uint_as_float(v1 << 16) +
          __uint_as_float(v2 << 16) + __uint_as_float(v3 << 16);
    a1 += __uint_as_float(v0 & 0xffff0000u) + __uint_as_float(v1 & 0xffff0000u) +
          __uint_as_float(v2 & 0xffff0000u) + __uint_as_float(v3 & 0xffff0000u);
  }
  for (; i < n; ++i) {
    uint32_t v = xw[(size_t)esrc[start + i] * 64 + c];
    a0 += __uint_as_float(v << 16);
    a1 += __uint_as_float(v & 0xffff0000u);
  }
  float inv = 1.0f / fmaxf((float)n, 1.0f);
  a0 *= inv; a1 *= inv;
  uint32_t packed = (uint32_t)f2bf(a0) | ((uint32_t)f2bf(a1) << 16);
  reinterpret_cast<uint32_t*>(agg)[(size_t)d * 64 + c] = packed;
}

// ---------------- gather-mean (bf16 in), layer 2: 32 lanes/dst, f32 out ----
__global__ __launch_bounds__(256) void sage_gather2(
    const uint16_t* __restrict__ t2, const int* __restrict__ esrc,
    const int* __restrict__ R, const int* __restrict__ part,
    const int* __restrict__ deg, float* __restrict__ agg) {
  int d = blockIdx.x * 8 + (threadIdx.x >> 5);
  int c = threadIdx.x & 31;
  if (d >= CN2) return;
  int start = R[d] + part[d >> 9], n = deg[d];
  const uint32_t* tw = reinterpret_cast<const uint32_t*>(t2);
  float a0 = 0.f, a1 = 0.f;
  int i = 0;
  for (; i + 4 <= n; i += 4) {
    int s0 = esrc[start + i + 0];
    int s1 = esrc[start + i + 1];
    int s2 = esrc[start + i + 2];
    int s3 = esrc[start + i + 3];
    uint32_t v0 = tw[(size_t)s0 * 32 + c];
    uint32_t v1 = tw[(size_t)s1 * 32 + c];
    uint32_t v2 = tw[(size_t)s2 * 32 + c];
    uint32_t v3 = tw[(size_t)s3 * 32 + c];
    a0 += __uint_as_float(v0 << 16) + __uint_as_float(v1 << 16) +
          __uint_as_float(v2 << 16) + __uint_as_float(v3 << 16);
    a1 += __uint_as_float(v0 & 0xffff0000u) + __uint_as_float(v1 & 0xffff0000u) +
          __uint_as_float(v2 & 0xffff0000u) + __uint_as_float(v3 & 0xffff0000u);
  }
  for (; i < n; ++i) {
    uint32_t v = tw[(size_t)esrc[start + i] * 32 + c];
    a0 += __uint_as_float(v << 16);
    a1 += __uint_as_float(v & 0xffff0000u);
  }
  float inv = 1.0f / fmaxf((float)n, 1.0f);
  float2 o = {a0 * inv, a1 * inv};
  reinterpret_cast<float2*>(agg)[(size_t)d * 32 + c] = o;
}

// ---------------- MEGA kernel (R11: 32x32x16 MFMA, fused phase 2) ----------------
// Each wave owns 32 rows (782 blocks x 4 waves). Per col-group n (8 of 32 cols):
//   h1-tile = relu([agg|x](32x256) @ wcat[n]^T + b)   (16 chained-x2 MFMAs)
//   -> per-wave 2.5 KB LDS transpose (C-layout write, A-frag read; no barriers)
//   -> acc2[0..3] += h1tile @ w2cat[:, n-slice]       (4-8 MFMAs)
// Epilogue: direct stores; each half-wave writes 64-B (t2) / 128-B (out) runs.
__global__ __launch_bounds__(256, 2) void sage_mega(
    const uint16_t* __restrict__ agg, const uint16_t* __restrict__ xbf,
    const uint16_t* __restrict__ wcat, const uint16_t* __restrict__ w2cat,
    const float* __restrict__ bias, uint16_t* __restrict__ t2,
    float* __restrict__ outp) {
  __shared__ uint16_t h1t[4 * 32 * 40];   // 10240 B; per-wave 32x40 tile
  const int tid = threadIdx.x;
  const int w = tid >> 6;
  const int lane = tid & 63;
  const int lcol = lane & 31;             // A-row / B-col / C-col
  const int hi = lane >> 5;               // k-half (frags) / row +4 (C)
  const int row0 = blockIdx.x * 128 + w * 32;
  uint16_t* hw = &h1t[w * (32 * 40)];

  // A fragments: 16 k-tiles of K=16 from [agg | x]; lane: row=lcol, k=hi*8..+7
  int arow = row0 + lcol;
  arow = arow < CN1 ? arow : CN1 - 1;
  bf16x8 afr[16];
#pragma unroll
  for (int t = 0; t < 16; ++t) {
    const uint16_t* Asrc = (t < 8) ? agg : xbf;
    const int koff = (t < 8) ? t * 16 : t * 16 - 128;
    afr[t] = *reinterpret_cast<const bf16x8*>(
        Asrc + (size_t)arow * CD_IN + koff + hi * 8);
  }

  const bool do_out = (row0 < CN2);       // CN2 % 32 == 0 -> wave-uniform
  f32x16 acc2[4];
#pragma unroll
  for (int j = 0; j < 4; ++j) acc2[j] = (f32x16)0.0f;

#pragma unroll
  for (int n = 0; n < 8; ++n) {
    // ---- phase 1: 32x32 h1 C-tile for col-group n (2 partial acc chains) ----
    const float bb = bias[n * 32 + lcol];
    f32x16 p0 = (f32x16)0.0f, p1 = (f32x16)0.0f;
#pragma unroll
    for (int t = 0; t < 16; t += 2) {
      bf16x8 b0 = *reinterpret_cast<const bf16x8*>(
          wcat + (size_t)(n * 32 + lcol) * 256 + t * 16 + hi * 8);
      bf16x8 b1 = *reinterpret_cast<const bf16x8*>(
          wcat + (size_t)(n * 32 + lcol) * 256 + (t + 1) * 16 + hi * 8);
      p0 = __builtin_amdgcn_mfma_f32_32x32x16_bf16(afr[t], b0, p0, 0, 0, 0);
      p1 = __builtin_amdgcn_mfma_f32_32x32x16_bf16(afr[t + 1], b1, p1, 0, 0, 0);
    }
    // bias + relu -> bf16 -> per-wave LDS transpose tile (C layout: m74/m101)
#pragma unroll
    for (int r = 0; r < 16; ++r) {
      float v = fmaxf(p0[r] + p1[r] + bb, 0.0f);
      int R = (r & 3) + 8 * (r >> 2) + 4 * hi;
      hw[R * 40 + lcol] = f2bf(v);
    }
    // read back as phase-2 A-frags (k = n*32 + {0..15, 16..31})
    bf16x8 a2q0 = *reinterpret_cast<const bf16x8*>(&hw[lcol * 40 + hi * 8]);
    bf16x8 a2q1 = *reinterpret_cast<const bf16x8*>(&hw[lcol * 40 + 16 + hi * 8]);
    // ---- phase 2 partial: acc2[j] += h1tile @ w2cat[j-group, k=n*32..] ----
    {
      bf16x8 c0 = *reinterpret_cast<const bf16x8*>(
          w2cat + (size_t)(0 * 32 + lcol) * 256 + n * 32 + hi * 8);
      bf16x8 c1 = *reinterpret_cast<const bf16x8*>(
          w2cat + (size_t)(0 * 32 + lcol) * 256 + n * 32 + 16 + hi * 8);
      acc2[0] = __builtin_amdgcn_mfma_f32_32x32x16_bf16(a2q0, c0, acc2[0], 0, 0, 0);
      acc2[0] = __builtin_amdgcn_mfma_f32_32x32x16_bf16(a2q1, c1, acc2[0], 0, 0, 0);
    }
    {
      bf16x8 c0 = *reinterpret_cast<const bf16x8*>(
          w2cat + (size_t)(1 * 32 + lcol) * 256 + n * 32 + hi * 8);
      bf16x8 c1 = *reinterpret_cast<const bf16x8*>(
          w2cat + (size_t)(1 * 32 + lcol) * 256 + n * 32 + 16 + hi * 8);
      acc2[1] = __builtin_amdgcn_mfma_f32_32x32x16_bf16(a2q0, c0, acc2[1], 0, 0, 0);
      acc2[1] = __builtin_amdgcn_mfma_f32_32x32x16_bf16(a2q1, c1, acc2[1], 0, 0, 0);
    }
    if (do_out) {
      {
        bf16x8 c0 = *reinterpret_cast<const bf16x8*>(
            w2cat + (size_t)(2 * 32 + lcol) * 256 + n * 32 + hi * 8);
        bf16x8 c1 = *reinterpret_cast<const bf16x8*>(
            w2cat + (size_t)(2 * 32 + lcol) * 256 + n * 32 + 16 + hi * 8);
        acc2[2] = __builtin_amdgcn_mfma_f32_32x32x16_bf16(a2q0, c0, acc2[2], 0, 0, 0);
        acc2[2] = __builtin_amdgcn_mfma_f32_32x32x16_bf16(a2q1, c1, acc2[2], 0, 0, 0);
      }
      {
        bf16x8 c0 = *reinterpret_cast<const bf16x8*>(
            w2cat + (size_t)(3 * 32 + lcol) * 256 + n * 32 + hi * 8);
        bf16x8 c1 = *reinterpret_cast<const bf16x8*>(
            w2cat + (size_t)(3 * 32 + lcol) * 256 + n * 32 + 16 + hi * 8);
        acc2[3] = __builtin_amdgcn_mfma_f32_32x32x16_bf16(a2q0, c0, acc2[3], 0, 0, 0);
        acc2[3] = __builtin_amdgcn_mfma_f32_32x32x16_bf16(a2q1, c1, acc2[3], 0, 0, 0);
      }
    }
  }

  // ---- epilogue: direct stores (64-B t2 / 128-B out runs per half-wave) ----
#pragma unroll
  for (int r = 0; r < 16; ++r) {
    int R = (r & 3) + 8 * (r >> 2) + 4 * hi;
    int rg = row0 + R;
    if (rg < CN1) {
      t2[(size_t)rg * 64 + lcol] = f2bf(acc2[0][r]);
      t2[(size_t)rg * 64 + 32 + lcol] = f2bf(acc2[1][r]);
    }
  }
  if (do_out) {
#pragma unroll
    for (int r = 0; r < 16; ++r) {
      int R = (r & 3) + 8 * (r >> 2) + 4 * hi;
      int rg = row0 + R;
      outp[(size_t)rg * 64 + lcol] = acc2[2][r];
      outp[(size_t)rg * 64 + 32 + lcol] = acc2[3][r];
    }
  }
}

// ---------------- finalize: out = log_softmax(out + agg2 + b2) ----------------
__global__ __launch_bounds__(256) void sage_finalize(
    const float* __restrict__ agg2, const float* __restrict__ b,
    float* __restrict__ out) {
  int row = blockIdx.x * 4 + (threadIdx.x >> 6);
  int lane = threadIdx.x & 63;
  if (row >= CN2) return;
  size_t o = (size_t)row * CD_OUT + lane;
  float v = out[o] + agg2[o] + b[lane];
  float m = v;
#pragma unroll
  for (int d = 32; d > 0; d >>= 1) m = fmaxf(m, __shfl_xor(m, d));
  float e = expf(v - m);
  float s = e;
#pragma unroll
  for (int d = 32; d > 0; d >>= 1) s += __shfl_xor(s, d);
  out[o] = v - m - logf(s);
}

extern "C" void kernel_launch(void* const* d_in, const int* in_sizes, int n_in,
                              void* d_out, int out_size, void* d_ws, size_t ws_size,
                              hipStream_t stream) {
  const float* x    = (const float*)d_in[0];
  const int* src1   = (const int*)d_in[1];
  const int* dst1   = (const int*)d_in[2];
  const int* src2   = (const int*)d_in[3];
  const int* dst2   = (const int*)d_in[4];
  const float* W_l1 = (const float*)d_in[5];
  const float* b_l1 = (const float*)d_in[6];
  const float* W_r1 = (const float*)d_in[7];
  const float* W_l2 = (const float*)d_in[8];
  const float* b_l2 = (const float*)d_in[9];
  const float* W_r2 = (const float*)d_in[10];
  float* out = (float*)d_out;
  char* base = (char*)d_ws;

  // ---- workspace layout (bytes), ~111.5 MB ----
  uint16_t* x_bf  = (uint16_t*)base;                       // 51.2 MB
  uint16_t* t2_bf = (uint16_t*)(base + 51200000);          // 12.8 MB
  uint32_t* pairs1= (uint32_t*)(base + 64000000);          // 6.4 MB (E1*4)
  uint32_t* pairs2= (uint32_t*)(base + 70400000);          // 1.28 MB (E2*4)
  uint16_t* agg_bf= (uint16_t*)(base + 71680000);          // 25.6 MB
  float* agg2     = (float*)(base + 97280000);             // 5.12 MB
  int* deg1 = (int*)(base + 102400000);                    // 400 KB
  int* R1   = (int*)(base + 102800000);                    // 400 KB
  int* esrc1= (int*)(base + 103200000);                    // 6.4 MB
  int* deg2 = (int*)(base + 109600000);                    // 80 KB
  int* R2   = (int*)(base + 109680000);                    // 80 KB
  int* esrc2= (int*)(base + 109760000);                    // 1.28 MB
  int* H1   = (int*)(base + 111040000);                    // 200,704 B
  int* H2   = (int*)(base + 111240704);                    // 10,240 B
  char* misc = base + 111250944;
  int* T1  = (int*)(misc);
  int* Bb1 = (int*)(misc + 1024);
  int* T2  = (int*)(misc + 2048);
  int* Bb2 = (int*)(misc + 3072);
  int* part1 = (int*)(misc + 4096);
  int* part2 = (int*)(misc + 5120);
  uint16_t* wcat  = (uint16_t*)(misc + 6144);              // 128 KB
  uint16_t* w2cat = wcat + 65536;                          // 64 KB

  if (ws_size < 112000000u) return;

  // ---- converts ----
  cvt_f32_bf16_v4<<<(CN0 * CD_IN / 4 + 255) / 256, 256, 0, stream>>>(x, x_bf, CN0 * CD_IN / 4);
  cvt_weights<<<384, 256, 0, stream>>>(W_l1, W_r1, W_l2, W_r2, wcat, w2cat);

  // ---- dual-layer CSR build ----
  csr_count<<<G1 + G2, 256, 0, stream>>>(dst1, dst2, H1, H2);
  csr_scan<<<NBK1 + NBK2, 256, 0, stream>>>(H1, H2, T1, T2);
  csr_base<<<2, 256, 0, stream>>>(T1, T2, Bb1, Bb2);
  csr_place<<<G1 + G2, 256, 0, stream>>>(src1, dst1, src2, dst2, H1, H2,
                                         Bb1, Bb2, pairs1, pairs2);
  csr_bdeg<<<NBK1 + NBK2, 256, 0, stream>>>(pairs1, pairs2, Bb1, Bb2, T1, T2,
                                            deg1, deg2);
  csr_scan_local<<<NBK1 + NBK2, 256, 0, stream>>>(deg1, deg2, R1, R2, part1, part2);
  csr_scan_part<<<2, 256, 0, stream>>>(part1, part2);
  csr_bplace<<<NBK1 + NBK2, 256, 0, stream>>>(pairs1, pairs2, Bb1, Bb2, T1, T2,
                                              R1, R2, part1, part2, esrc1, esrc2);

  // ---- gather1 -> mega -> gather2 -> finalize ----
  sage_gather1<<<(CN1 + 3) / 4, 256, 0, stream>>>(x_bf, esrc1, R1, part1, deg1, agg_bf);
  sage_mega<<<(CN1 + 127) / 128, 256, 0, stream>>>(
      agg_bf, x_bf, wcat, w2cat, b_l1, t2_bf, out);
  sage_gather2<<<(CN2 + 7) / 8, 256, 0, stream>>>(t2_bf, esrc2, R2, part2, deg2, agg2);
  sage_finalize<<<(CN2 + 3) / 4, 256, 0, stream>>>(agg2, b_l2, out);
}

// Round 12
// 212.237 us; speedup vs baseline: 1.5287x; 1.2429x over previous
//
#include <hip/hip_runtime.h>
#include <stdint.h>

// SAGE_876173328847: 2-layer bipartite SAGEConv (mean agg) + log_softmax.
// N0=200000, N1=100000, N2=20000, E1=1.6M, E2=320K, D_IN=128, D_H=256, D_OUT=64.
//
// R1: atomic scatter -> CSR build + gather (3309 -> 667 us).
// R2/R3: bf16 heavy path + MFMA GEMMs (667 -> 547 us).
// R4: fused mega-kernel, h1 lives only in LDS (547 -> 472 us).
// R7: scan-based multi-split CSR build, zero global atomics (-> 366 us).
// R8: spill-free mega (-> 347). R9: launch fusion 22->14 (-> 285).
// R11: 32x32x16 MFMA, 32 rows/wave, fused phase 2 (-> 263.8; mega 87 us but
//      still latency-bound on dependent 16B L2 B-fragment loads).
// R12: weights pre-packed in FRAGMENT ORDER (wfragG/w2fragG); mega stages
//      64 KB halves into LDS via coalesced 1KB/wave copies; B-frags become
//      contiguous conflict-free ds_read_b128. a2 frags kept in registers;
//      phase 2 j-outer with 2 live accumulators. 6 barriers/block.

#define CN0 200000
#define CN1 100000
#define CN2 20000
#define CE1 1600000
#define CE2 320000
#define CD_IN 128
#define CD_H 256
#define CD_OUT 64

// multi-split geometry: bucket = dst >> 9 (512 dsts per bucket)
#define NBK1 196          // ceil(N1/512)
#define NBK2 40           // ceil(N2/512)
#define G1 256
#define G2 64
#define CHUNK1 6250       // E1 / G1
#define CHUNK2 5000       // E2 / G2

typedef __bf16 bf16x8 __attribute__((ext_vector_type(8)));
typedef float f32x4 __attribute__((ext_vector_type(4)));
typedef float f32x16 __attribute__((ext_vector_type(16)));
typedef uint16_t u16x4 __attribute__((ext_vector_type(4)));

__device__ inline uint16_t f2bf(float f) {
  uint32_t u = __float_as_uint(f);
  return (uint16_t)((u + 0x7fffu + ((u >> 16) & 1u)) >> 16);
}

// ---------------- dtype converts ----------------
__global__ __launch_bounds__(256) void cvt_f32_bf16_v4(
    const float* __restrict__ in, uint16_t* __restrict__ out, int n4) {
  int i = blockIdx.x * 256 + threadIdx.x;
  if (i >= n4) return;
  float4 v = reinterpret_cast<const float4*>(in)[i];
  u16x4 o = {f2bf(v.x), f2bf(v.y), f2bf(v.z), f2bf(v.w)};
  reinterpret_cast<u16x4*>(out)[i] = o;
}

// weights -> FRAGMENT-ORDER bf16 arrays.
// wfragG : [8 n][16 t][64 lane][8] ; value = Wcat[n*32+(lane&31)][t*16+(lane>>5)*8+e]
//          (Wcat row r: cols 0..127 = Wl1[r], 128..255 = Wr1[r])
// w2fragG: [4 j][16 tt][64 lane][8]; value = W2cat[j*32+(lane&31)][tt*16+(lane>>5)*8+e]
//          (W2cat rows 0..63 = Wl2, 64..127 = Wr2)
__global__ __launch_bounds__(256) void cvt_weights(
    const float* __restrict__ Wl1, const float* __restrict__ Wr1,
    const float* __restrict__ Wl2, const float* __restrict__ Wr2,
    uint16_t* __restrict__ wfragG, uint16_t* __restrict__ w2fragG) {
  int c = blockIdx.x * 256 + threadIdx.x;   // 12288 chunks total
  if (c >= 12288) return;
  uint16_t o[8];
  if (c < 8192) {
    int lane = c & 63, t = (c >> 6) & 15, n = c >> 10;
    int row = n * 32 + (lane & 31);
    int kk = t * 16 + (lane >> 5) * 8;
    const float* srcp = (kk < 128) ? (Wl1 + (size_t)row * 128 + kk)
                                   : (Wr1 + (size_t)row * 128 + (kk - 128));
#pragma unroll
    for (int e = 0; e < 8; ++e) o[e] = f2bf(srcp[e]);
    *reinterpret_cast<int4*>(wfragG + (size_t)c * 8) = *reinterpret_cast<int4*>(o);
  } else {
    int cc = c - 8192;                      // 0..4095
    int lane = cc & 63, tt = (cc >> 6) & 15, j = cc >> 10;
    int row = j * 32 + (lane & 31);
    int kk = tt * 16 + (lane >> 5) * 8;
    const float* srcp = (row < 64) ? (Wl2 + (size_t)row * 256 + kk)
                                   : (Wr2 + (size_t)(row - 64) * 256 + kk);
#pragma unroll
    for (int e = 0; e < 8; ++e) o[e] = f2bf(srcp[e]);
    *reinterpret_cast<int4*>(w2fragG + (size_t)cc * 8) = *reinterpret_cast<int4*>(o);
  }
}

// ---------------- dual-layer scan-based multi-split ----------------
__global__ __launch_bounds__(256) void csr_count(
    const int* __restrict__ dst1, const int* __restrict__ dst2,
    int* __restrict__ H1, int* __restrict__ H2) {
  __shared__ int hist[256];
  int g = blockIdx.x, t = threadIdx.x;
  const int* dst; int* H; int E, nb, chunk;
  if (g < G1) { dst = dst1; H = H1; E = CE1; nb = NBK1; chunk = CHUNK1; }
  else { g -= G1; dst = dst2; H = H2; E = CE2; nb = NBK2; chunk = CHUNK2; }
  hist[t] = 0;
  __syncthreads();
  int e0 = g * chunk, e1 = min(e0 + chunk, E);
  for (int e = e0 + t; e < e1; e += 256) atomicAdd(&hist[dst[e] >> 9], 1);
  __syncthreads();
  if (t < nb) H[g * nb + t] = hist[t];
}

__global__ __launch_bounds__(256) void csr_scan(
    int* __restrict__ H1, int* __restrict__ H2,
    int* __restrict__ T1, int* __restrict__ T2) {
  __shared__ int sm[256];
  int b = blockIdx.x, t = threadIdx.x;
  int* H; int* T; int nb, G;
  if (b < NBK1) { H = H1; T = T1; nb = NBK1; G = G1; }
  else { b -= NBK1; H = H2; T = T2; nb = NBK2; G = G2; }
  int v = (t < G) ? H[t * nb + b] : 0;
  sm[t] = v;
  __syncthreads();
#pragma unroll
  for (int off = 1; off < 256; off <<= 1) {
    int u = (t >= off) ? sm[t - off] : 0;
    __syncthreads();
    sm[t] += u;
    __syncthreads();
  }
  if (t < G) H[t * nb + b] = sm[t] - v;  // exclusive over chunks
  if (t == 255) T[b] = sm[255];          // bucket total
}

__global__ __launch_bounds__(256) void csr_base(
    const int* __restrict__ T1, const int* __restrict__ T2,
    int* __restrict__ Bb1, int* __restrict__ Bb2) {
  __shared__ int sm[256];
  int t = threadIdx.x;
  const int* T; int* Bb; int nb;
  if (blockIdx.x == 0) { T = T1; Bb = Bb1; nb = NBK1; }
  else { T = T2; Bb = Bb2; nb = NBK2; }
  int v = (t < nb) ? T[t] : 0;
  sm[t] = v;
  __syncthreads();
#pragma unroll
  for (int off = 1; off < 256; off <<= 1) {
    int u = (t >= off) ? sm[t - off] : 0;
    __syncthreads();
    sm[t] += u;
    __syncthreads();
  }
  if (t < nb) Bb[t] = sm[t] - v;
}

__global__ __launch_bounds__(256) void csr_place(
    const int* __restrict__ src1, const int* __restrict__ dst1,
    const int* __restrict__ src2, const int* __restrict__ dst2,
    const int* __restrict__ H1, const int* __restrict__ H2,
    const int* __restrict__ Bb1, const int* __restrict__ Bb2,
    uint32_t* __restrict__ pairs1, uint32_t* __restrict__ pairs2) {
  __shared__ int curs[256];
  int g = blockIdx.x, t = threadIdx.x;
  const int* src; const int* dst; const int* H; const int* Bb;
  uint32_t* pairs; int E, nb, chunk;
  if (g < G1) { src = src1; dst = dst1; H = H1; Bb = Bb1; pairs = pairs1;
                E = CE1; nb = NBK1; chunk = CHUNK1; }
  else { g -= G1; src = src2; dst = dst2; H = H2; Bb = Bb2; pairs = pairs2;
         E = CE2; nb = NBK2; chunk = CHUNK2; }
  if (t < nb) curs[t] = Bb[t] + H[g * nb + t];
  __syncthreads();
  int e0 = g * chunk, e1 = min(e0 + chunk, E);
  for (int e = e0 + t; e < e1; e += 256) {
    int d = dst[e];
    int b = d >> 9;
    int p = atomicAdd(&curs[b], 1);
    pairs[p] = (uint32_t)src[e] | ((uint32_t)(d & 511) << 18);
  }
}

__global__ __launch_bounds__(256) void csr_bdeg(
    const uint32_t* __restrict__ pairs1, const uint32_t* __restrict__ pairs2,
    const int* __restrict__ Bb1, const int* __restrict__ Bb2,
    const int* __restrict__ T1, const int* __restrict__ T2,
    int* __restrict__ deg1, int* __restrict__ deg2) {
  __shared__ int cnt[512];
  int b = blockIdx.x, t = threadIdx.x;
  const uint32_t* pairs; const int* Bb; const int* T; int* deg; int ndst;
  if (b < NBK1) { pairs = pairs1; Bb = Bb1; T = T1; deg = deg1; ndst = CN1; }
  else { b -= NBK1; pairs = pairs2; Bb = Bb2; T = T2; deg = deg2; ndst = CN2; }
  cnt[t] = 0;
  cnt[t + 256] = 0;
  __syncthreads();
  int s0 = Bb[b], n = T[b];
  for (int i = t; i < n; i += 256) atomicAdd(&cnt[pairs[s0 + i] >> 18], 1);
  __syncthreads();
  int d0 = b << 9;
#pragma unroll
  for (int j = 0; j < 2; ++j) {
    int dd = d0 + t + j * 256;
    if (dd < ndst) deg[dd] = cnt[t + j * 256];
  }
}

__global__ __launch_bounds__(256) void csr_scan_local(
    const int* __restrict__ deg1, const int* __restrict__ deg2,
    int* __restrict__ R1, int* __restrict__ R2,
    int* __restrict__ part1, int* __restrict__ part2) {
  __shared__ int sm[256];
  int b = blockIdx.x, t = threadIdx.x;
  const int* deg; int* R; int* part; int N;
  if (b < NBK1) { deg = deg1; R = R1; part = part1; N = CN1; }
  else { b -= NBK1; deg = deg2; R = R2; part = part2; N = CN2; }
  int base = b * 512;
  int i0 = base + 2 * t, i1 = base + 2 * t + 1;
  int a = (i0 < N) ? deg[i0] : 0;
  int bb = (i1 < N) ? deg[i1] : 0;
  int s = a + bb;
  sm[t] = s;
  __syncthreads();
#pragma unroll
  for (int off = 1; off < 256; off <<= 1) {
    int v = (t >= off) ? sm[t - off] : 0;
    __syncthreads();
    sm[t] += v;
    __syncthreads();
  }
  int excl = sm[t] - s;
  if (i0 < N) R[i0] = excl;
  if (i1 < N) R[i1] = excl + a;
  if (t == 255) part[b] = sm[255];
}

__global__ __launch_bounds__(256) void csr_scan_part(
    int* __restrict__ part1, int* __restrict__ part2) {
  __shared__ int sm[256];
  int t = threadIdx.x;
  int* part; int B;
  if (blockIdx.x == 0) { part = part1; B = NBK1; }
  else { part = part2; B = NBK2; }
  int v = (t < B) ? part[t] : 0;
  sm[t] = v;
  __syncthreads();
#pragma unroll
  for (int off = 1; off < 256; off <<= 1) {
    int u = (t >= off) ? sm[t - off] : 0;
    __syncthreads();
    sm[t] += u;
    __syncthreads();
  }
  if (t < B) part[t] = sm[t] - v;
}

// bplace with addback folded in: final offset = R[dd] + part[bucket]
__global__ __launch_bounds__(256) void csr_bplace(
    const uint32_t* __restrict__ pairs1, const uint32_t* __restrict__ pairs2,
    const int* __restrict__ Bb1, const int* __restrict__ Bb2,
    const int* __restrict__ T1, const int* __restrict__ T2,
    const int* __restrict__ R1, const int* __restrict__ R2,
    const int* __restrict__ part1, const int* __restrict__ part2,
    int* __restrict__ esrc1, int* __restrict__ esrc2) {
  __shared__ int curs[512];
  int b = blockIdx.x, t = threadIdx.x;
  const uint32_t* pairs; const int* Bb; const int* T; const int* R;
  const int* part; int* esrc; int ndst;
  if (b < NBK1) { pairs = pairs1; Bb = Bb1; T = T1; R = R1; part = part1;
                  esrc = esrc1; ndst = CN1; }
  else { b -= NBK1; pairs = pairs2; Bb = Bb2; T = T2; R = R2; part = part2;
         esrc = esrc2; ndst = CN2; }
  int d0 = b << 9;
  int pb = part[b];
#pragma unroll
  for (int j = 0; j < 2; ++j) {
    int dd = d0 + t + j * 256;
    curs[t + j * 256] = (dd < ndst) ? R[dd] + pb : 0;
  }
  __syncthreads();
  int s0 = Bb[b], n = T[b];
  for (int i = t; i < n; i += 256) {
    uint32_t pk = pairs[s0 + i];
    int p = atomicAdd(&curs[pk >> 18], 1);
    esrc[p] = (int)(pk & 0x3FFFFu);
  }
}

// ---------------- gather-mean (bf16 in), layer 1: 64 lanes/dst ----------------
__global__ __launch_bounds__(256) void sage_gather1(
    const uint16_t* __restrict__ xbf, const int* __restrict__ esrc,
    const int* __restrict__ R, const int* __restrict__ part,
    const int* __restrict__ deg, uint16_t* __restrict__ agg) {
  int d = blockIdx.x * 4 + (threadIdx.x >> 6);
  int c = threadIdx.x & 63;
  if (d >= CN1) return;
  int start = R[d] + part[d >> 9], n = deg[d];
  const uint32_t* xw = reinterpret_cast<const uint32_t*>(xbf);
  float a0 = 0.f, a1 = 0.f;
  int i = 0;
  for (; i + 4 <= n; i += 4) {
    int s0 = esrc[start + i + 0];
    int s1 = esrc[start + i + 1];
    int s2 = esrc[start + i + 2];
    int s3 = esrc[start + i + 3];
    uint32_t v0 = xw[(size_t)s0 * 64 + c];
    uint32_t v1 = xw[(size_t)s1 * 64 + c];
    uint32_t v2 = xw[(size_t)s2 * 64 + c];
    uint32_t v3 = xw[(size_t)s3 * 64 + c];
    a0 += __uint_as_float(v0 << 16) + __uint_as_float(v1 << 16) +
          __uint_as_float(v2 << 16) + __uint_as_float(v3 << 16);
    a1 += __uint_as_float(v0 & 0xffff0000u) + __uint_as_float(v1 & 0xffff0000u) +
          __uint_as_float(v2 & 0xffff0000u) + __uint_as_float(v3 & 0xffff0000u);
  }
  for (; i < n; ++i) {
    uint32_t v = xw[(size_t)esrc[start + i] * 64 + c];
    a0 += __uint_as_float(v << 16);
    a1 += __uint_as_float(v & 0xffff0000u);
  }
  float inv = 1.0f / fmaxf((float)n, 1.0f);
  a0 *= inv; a1 *= inv;
  uint32_t packed = (uint32_t)f2bf(a0) | ((uint32_t)f2bf(a1) << 16);
  reinterpret_cast<uint32_t*>(agg)[(size_t)d * 64 + c] = packed;
}

// ---------------- gather-mean (bf16 in), layer 2: 32 lanes/dst, f32 out ----
__global__ __launch_bounds__(256) void sage_gather2(
    const uint16_t* __restrict__ t2, const int* __restrict__ esrc,
    const int* __restrict__ R, const int* __restrict__ part,
    const int* __restrict__ deg, float* __restrict__ agg) {
  int d = blockIdx.x * 8 + (threadIdx.x >> 5);
  int c = threadIdx.x & 31;
  if (d >= CN2) return;
  int start = R[d] + part[d >> 9], n = deg[d];
  const uint32_t* tw = reinterpret_cast<const uint32_t*>(t2);
  float a0 = 0.f, a1 = 0.f;
  int i = 0;
  for (; i + 4 <= n; i += 4) {
    int s0 = esrc[start + i + 0];
    int s1 = esrc[start + i + 1];
    int s2 = esrc[start + i + 2];
    int s3 = esrc[start + i + 3];
    uint32_t v0 = tw[(size_t)s0 * 32 + c];
    uint32_t v1 = tw[(size_t)s1 * 32 + c];
    uint32_t v2 = tw[(size_t)s2 * 32 + c];
    uint32_t v3 = tw[(size_t)s3 * 32 + c];
    a0 += __uint_as_float(v0 << 16) + __uint_as_float(v1 << 16) +
          __uint_as_float(v2 << 16) + __uint_as_float(v3 << 16);
    a1 += __uint_as_float(v0 & 0xffff0000u) + __uint_as_float(v1 & 0xffff0000u) +
          __uint_as_float(v2 & 0xffff0000u) + __uint_as_float(v3 & 0xffff0000u);
  }
  for (; i < n; ++i) {
    uint32_t v = tw[(size_t)esrc[start + i] * 32 + c];
    a0 += __uint_as_float(v << 16);
    a1 += __uint_as_float(v & 0xffff0000u);
  }
  float inv = 1.0f / fmaxf((float)n, 1.0f);
  float2 o = {a0 * inv, a1 * inv};
  reinterpret_cast<float2*>(agg)[(size_t)d * 32 + c] = o;
}

// ---------------- MEGA kernel (R12: LDS-staged fragment-order W) ----------------
// Each wave owns 32 rows (782 blocks x 4 waves). W1 staged in two 64 KB halves,
// w2 staged once (reusing the same buffer). All B-frag reads are contiguous
// conflict-free ds_read_b128. h1 A-frags (a2[16]) kept in registers.
__global__ __launch_bounds__(256, 2) void sage_mega(
    const uint16_t* __restrict__ agg, const uint16_t* __restrict__ xbf,
    const uint16_t* __restrict__ wfragG, const uint16_t* __restrict__ w2fragG,
    const float* __restrict__ bias, uint16_t* __restrict__ t2,
    float* __restrict__ outp) {
  __shared__ uint16_t wfrag[32768];       // 64 KB: 64 chunks x 512 shorts
  __shared__ uint16_t h1t[4 * 32 * 40];   // 10240 B; per-wave 32x40 transpose tile
  const int tid = threadIdx.x;
  const int w = tid >> 6;
  const int lane = tid & 63;
  const int lcol = lane & 31;             // A-row / B-col / C-col
  const int hi = lane >> 5;               // k-half (frags) / row +4 (C)
  const int row0 = blockIdx.x * 128 + w * 32;
  uint16_t* hw = &h1t[w * (32 * 40)];

  // A fragments: 16 k-tiles of K=16 from [agg | x]; lane: row=lcol, k=hi*8..+7
  int arow = row0 + lcol;
  arow = arow < CN1 ? arow : CN1 - 1;
  bf16x8 afr[16];
#pragma unroll
  for (int t = 0; t < 16; ++t) {
    const uint16_t* Asrc = (t < 8) ? agg : xbf;
    const int koff = (t < 8) ? t * 16 : t * 16 - 128;
    afr[t] = *reinterpret_cast<const bf16x8*>(
        Asrc + (size_t)arow * CD_IN + koff + hi * 8);
  }

  const bool do_out = (row0 < CN2);       // CN2 % 32 == 0 -> wave-uniform
  bf16x8 a2[16];                          // h1 A-frags, filled per n (static idx)

#pragma unroll
  for (int h = 0; h < 2; ++h) {
    // stage half h of W1 fragments: 64 chunks x 1 KB, 16 per wave, coalesced
#pragma unroll
    for (int i = 0; i < 16; ++i) {
      int cc = i * 4 + w;
      int4 v = *reinterpret_cast<const int4*>(
          wfragG + (size_t)(h * 64 + cc) * 512 + lane * 8);
      *reinterpret_cast<int4*>(&wfrag[cc * 512 + lane * 8]) = v;
    }
    __syncthreads();
#pragma unroll
    for (int nn = 0; nn < 4; ++nn) {
      const int n = h * 4 + nn;
      const float bb = bias[n * 32 + lcol];
      f32x16 p0 = (f32x16)0.0f, p1 = (f32x16)0.0f;
#pragma unroll
      for (int t = 0; t < 16; t += 2) {
        bf16x8 b0 = *reinterpret_cast<const bf16x8*>(
            &wfrag[((nn * 16 + t) * 64 + lane) * 8]);
        bf16x8 b1 = *reinterpret_cast<const bf16x8*>(
            &wfrag[((nn * 16 + t + 1) * 64 + lane) * 8]);
        p0 = __builtin_amdgcn_mfma_f32_32x32x16_bf16(afr[t], b0, p0, 0, 0, 0);
        p1 = __builtin_amdgcn_mfma_f32_32x32x16_bf16(afr[t + 1], b1, p1, 0, 0, 0);
      }
      // bias + relu -> bf16 -> per-wave LDS transpose tile (C layout m74/m101)
#pragma unroll
      for (int r = 0; r < 16; ++r) {
        float v = fmaxf(p0[r] + p1[r] + bb, 0.0f);
        int R = (r & 3) + 8 * (r >> 2) + 4 * hi;
        hw[R * 40 + lcol] = f2bf(v);
      }
      // read back as phase-2 A-frags (k = n*32 + {0..15, 16..31})
      a2[n * 2 + 0] = *reinterpret_cast<const bf16x8*>(&hw[lcol * 40 + hi * 8]);
      a2[n * 2 + 1] = *reinterpret_cast<const bf16x8*>(&hw[lcol * 40 + 16 + hi * 8]);
    }
    __syncthreads();   // all waves done reading this half before overwrite
  }

  // stage w2 fragments (64 KB) into the same buffer
#pragma unroll
  for (int i = 0; i < 16; ++i) {
    int cc = i * 4 + w;
    int4 v = *reinterpret_cast<const int4*>(
        w2fragG + (size_t)cc * 512 + lane * 8);
    *reinterpret_cast<int4*>(&wfrag[cc * 512 + lane * 8]) = v;
  }
  __syncthreads();

  // ---- phase 2: jp=0 -> t2 cols (j=0,1); jp=1 -> out cols (j=2,3) ----
#pragma unroll
  for (int jp = 0; jp < 2; ++jp) {
    if (jp == 1 && !do_out) break;
    const int jA = jp * 2, jB = jp * 2 + 1;
    f32x16 aA = (f32x16)0.0f, aB = (f32x16)0.0f;
#pragma unroll
    for (int s = 0; s < 8; ++s) {
      bf16x8 c0A = *reinterpret_cast<const bf16x8*>(
          &wfrag[((jA * 16 + s * 2) * 64 + lane) * 8]);
      bf16x8 c1A = *reinterpret_cast<const bf16x8*>(
          &wfrag[((jA * 16 + s * 2 + 1) * 64 + lane) * 8]);
      bf16x8 c0B = *reinterpret_cast<const bf16x8*>(
          &wfrag[((jB * 16 + s * 2) * 64 + lane) * 8]);
      bf16x8 c1B = *reinterpret_cast<const bf16x8*>(
          &wfrag[((jB * 16 + s * 2 + 1) * 64 + lane) * 8]);
      aA = __builtin_amdgcn_mfma_f32_32x32x16_bf16(a2[s * 2], c0A, aA, 0, 0, 0);
      aB = __builtin_amdgcn_mfma_f32_32x32x16_bf16(a2[s * 2], c0B, aB, 0, 0, 0);
      aA = __builtin_amdgcn_mfma_f32_32x32x16_bf16(a2[s * 2 + 1], c1A, aA, 0, 0, 0);
      aB = __builtin_amdgcn_mfma_f32_32x32x16_bf16(a2[s * 2 + 1], c1B, aB, 0, 0, 0);
    }
    if (jp == 0) {
#pragma unroll
      for (int r = 0; r < 16; ++r) {
        int R = (r & 3) + 8 * (r >> 2) + 4 * hi;
        int rg = row0 + R;
        if (rg < CN1) {
          t2[(size_t)rg * 64 + lcol] = f2bf(aA[r]);
          t2[(size_t)rg * 64 + 32 + lcol] = f2bf(aB[r]);
        }
      }
    } else {
#pragma unroll
      for (int r = 0; r < 16; ++r) {
        int R = (r & 3) + 8 * (r >> 2) + 4 * hi;
        int rg = row0 + R;
        outp[(size_t)rg * 64 + lcol] = aA[r];
        outp[(size_t)rg * 64 + 32 + lcol] = aB[r];
      }
    }
  }
}

// ---------------- finalize: out = log_softmax(out + agg2 + b2) ----------------
__global__ __launch_bounds__(256) void sage_finalize(
    const float* __restrict__ agg2, const float* __restrict__ b,
    float* __restrict__ out) {
  int row = blockIdx.x * 4 + (threadIdx.x >> 6);
  int lane = threadIdx.x & 63;
  if (row >= CN2) return;
  size_t o = (size_t)row * CD_OUT + lane;
  float v = out[o] + agg2[o] + b[lane];
  float m = v;
#pragma unroll
  for (int d = 32; d > 0; d >>= 1) m = fmaxf(m, __shfl_xor(m, d));
  float e = expf(v - m);
  float s = e;
#pragma unroll
  for (int d = 32; d > 0; d >>= 1) s += __shfl_xor(s, d);
  out[o] = v - m - logf(s);
}

extern "C" void kernel_launch(void* const* d_in, const int* in_sizes, int n_in,
                              void* d_out, int out_size, void* d_ws, size_t ws_size,
                              hipStream_t stream) {
  const float* x    = (const float*)d_in[0];
  const int* src1   = (const int*)d_in[1];
  const int* dst1   = (const int*)d_in[2];
  const int* src2   = (const int*)d_in[3];
  const int* dst2   = (const int*)d_in[4];
  const float* W_l1 = (const float*)d_in[5];
  const float* b_l1 = (const float*)d_in[6];
  const float* W_r1 = (const float*)d_in[7];
  const float* W_l2 = (const float*)d_in[8];
  const float* b_l2 = (const float*)d_in[9];
  const float* W_r2 = (const float*)d_in[10];
  float* out = (float*)d_out;
  char* base = (char*)d_ws;

  // ---- workspace layout (bytes), ~111.5 MB ----
  uint16_t* x_bf  = (uint16_t*)base;                       // 51.2 MB
  uint16_t* t2_bf = (uint16_t*)(base + 51200000);          // 12.8 MB
  uint32_t* pairs1= (uint32_t*)(base + 64000000);          // 6.4 MB (E1*4)
  uint32_t* pairs2= (uint32_t*)(base + 70400000);          // 1.28 MB (E2*4)
  uint16_t* agg_bf= (uint16_t*)(base + 71680000);          // 25.6 MB
  float* agg2     = (float*)(base + 97280000);             // 5.12 MB
  int* deg1 = (int*)(base + 102400000);                    // 400 KB
  int* R1   = (int*)(base + 102800000);                    // 400 KB
  int* esrc1= (int*)(base + 103200000);                    // 6.4 MB
  int* deg2 = (int*)(base + 109600000);                    // 80 KB
  int* R2   = (int*)(base + 109680000);                    // 80 KB
  int* esrc2= (int*)(base + 109760000);                    // 1.28 MB
  int* H1   = (int*)(base + 111040000);                    // 200,704 B
  int* H2   = (int*)(base + 111240704);                    // 10,240 B
  char* misc = base + 111250944;
  int* T1  = (int*)(misc);
  int* Bb1 = (int*)(misc + 1024);
  int* T2  = (int*)(misc + 2048);
  int* Bb2 = (int*)(misc + 3072);
  int* part1 = (int*)(misc + 4096);
  int* part2 = (int*)(misc + 5120);
  uint16_t* wfragG  = (uint16_t*)(misc + 6144);            // 128 KB (frag order)
  uint16_t* w2fragG = wfragG + 65536;                      // 64 KB (frag order)

  if (ws_size < 112000000u) return;

  // ---- converts ----
  cvt_f32_bf16_v4<<<(CN0 * CD_IN / 4 + 255) / 256, 256, 0, stream>>>(x, x_bf, CN0 * CD_IN / 4);
  cvt_weights<<<48, 256, 0, stream>>>(W_l1, W_r1, W_l2, W_r2, wfragG, w2fragG);

  // ---- dual-layer CSR build ----
  csr_count<<<G1 + G2, 256, 0, stream>>>(dst1, dst2, H1, H2);
  csr_scan<<<NBK1 + NBK2, 256, 0, stream>>>(H1, H2, T1, T2);
  csr_base<<<2, 256, 0, stream>>>(T1, T2, Bb1, Bb2);
  csr_place<<<G1 + G2, 256, 0, stream>>>(src1, dst1, src2, dst2, H1, H2,
                                         Bb1, Bb2, pairs1, pairs2);
  csr_bdeg<<<NBK1 + NBK2, 256, 0, stream>>>(pairs1, pairs2, Bb1, Bb2, T1, T2,
                                            deg1, deg2);
  csr_scan_local<<<NBK1 + NBK2, 256, 0, stream>>>(deg1, deg2, R1, R2, part1, part2);
  csr_scan_part<<<2, 256, 0, stream>>>(part1, part2);
  csr_bplace<<<NBK1 + NBK2, 256, 0, stream>>>(pairs1, pairs2, Bb1, Bb2, T1, T2,
                                              R1, R2, part1, part2, esrc1, esrc2);

  // ---- gather1 -> mega -> gather2 -> finalize ----
  sage_gather1<<<(CN1 + 3) / 4, 256, 0, stream>>>(x_bf, esrc1, R1, part1, deg1, agg_bf);
  sage_mega<<<(CN1 + 127) / 128, 256, 0, stream>>>(
      agg_bf, x_bf, wfragG, w2fragG, b_l1, t2_bf, out);
  sage_gather2<<<(CN2 + 7) / 8, 256, 0, stream>>>(t2_bf, esrc2, R2, part2, deg2, agg2);
  sage_finalize<<<(CN2 + 3) / 4, 256, 0, stream>>>(agg2, b_l2, out);
}

// Round 13
// 196.125 us; speedup vs baseline: 1.6543x; 1.0822x over previous
//
#include <hip/hip_runtime.h>
#include <stdint.h>

// SAGE_876173328847: 2-layer bipartite SAGEConv (mean agg) + log_softmax.
// N0=200000, N1=100000, N2=20000, E1=1.6M, E2=320K, D_IN=128, D_H=256, D_OUT=64.
//
// R1: atomic scatter -> CSR build + gather (3309 -> 667 us).
// R2/R3: bf16 heavy path + MFMA GEMMs (667 -> 547 us).
// R4: fused mega-kernel, h1 lives only in LDS (547 -> 472 us).
// R7: scan-based multi-split CSR build, zero global atomics (-> 366 us).
// R8: spill-free mega (-> 347). R9: launch fusion 22->14 (-> 285).
// R11: 32x32x16 MFMA 32-rows/wave fused mega (-> 264).
// R12: fragment-order W + LDS staging; mega off the critical path (-> 212).
// R13: gather1 was latency-bound (MLP=4, 40% VALU, 38% HBM): 8-wide unroll
//      with dual accumulators. Fuse gather2+finalize (one kernel, no agg2
//      round-trip). Fuse converts. 14 -> 12 dispatches.

#define CN0 200000
#define CN1 100000
#define CN2 20000
#define CE1 1600000
#define CE2 320000
#define CD_IN 128
#define CD_H 256
#define CD_OUT 64

// multi-split geometry: bucket = dst >> 9 (512 dsts per bucket)
#define NBK1 196          // ceil(N1/512)
#define NBK2 40           // ceil(N2/512)
#define G1 256
#define G2 64
#define CHUNK1 6250       // E1 / G1
#define CHUNK2 5000       // E2 / G2

typedef __bf16 bf16x8 __attribute__((ext_vector_type(8)));
typedef float f32x4 __attribute__((ext_vector_type(4)));
typedef float f32x16 __attribute__((ext_vector_type(16)));
typedef uint16_t u16x4 __attribute__((ext_vector_type(4)));

__device__ inline uint16_t f2bf(float f) {
  uint32_t u = __float_as_uint(f);
  return (uint16_t)((u + 0x7fffu + ((u >> 16) & 1u)) >> 16);
}
__device__ inline float blo(uint32_t v) { return __uint_as_float(v << 16); }
__device__ inline float bhi(uint32_t v) { return __uint_as_float(v & 0xffff0000u); }

// ---------------- fused converts: x (25000 blocks) + weight frags (48) ----------
// wfragG : [8 n][16 t][64 lane][8] ; value = Wcat[n*32+(lane&31)][t*16+(lane>>5)*8+e]
// w2fragG: [4 j][16 tt][64 lane][8]; value = W2cat[j*32+(lane&31)][tt*16+(lane>>5)*8+e]
__global__ __launch_bounds__(256) void cvt_all(
    const float* __restrict__ x, const float* __restrict__ Wl1,
    const float* __restrict__ Wr1, const float* __restrict__ Wl2,
    const float* __restrict__ Wr2, uint16_t* __restrict__ x_bf,
    uint16_t* __restrict__ wfragG, uint16_t* __restrict__ w2fragG) {
  int blk = blockIdx.x;
  if (blk < 25000) {
    int i = blk * 256 + threadIdx.x;      // < 6,400,000 exactly
    float4 v = reinterpret_cast<const float4*>(x)[i];
    u16x4 o = {f2bf(v.x), f2bf(v.y), f2bf(v.z), f2bf(v.w)};
    reinterpret_cast<u16x4*>(x_bf)[i] = o;
    return;
  }
  int c = (blk - 25000) * 256 + threadIdx.x;   // 0..12287
  uint16_t o[8];
  if (c < 8192) {
    int lane = c & 63, t = (c >> 6) & 15, n = c >> 10;
    int row = n * 32 + (lane & 31);
    int kk = t * 16 + (lane >> 5) * 8;
    const float* srcp = (kk < 128) ? (Wl1 + (size_t)row * 128 + kk)
                                   : (Wr1 + (size_t)row * 128 + (kk - 128));
#pragma unroll
    for (int e = 0; e < 8; ++e) o[e] = f2bf(srcp[e]);
    *reinterpret_cast<int4*>(wfragG + (size_t)c * 8) = *reinterpret_cast<int4*>(o);
  } else {
    int cc = c - 8192;                    // 0..4095
    int lane = cc & 63, tt = (cc >> 6) & 15, j = cc >> 10;
    int row = j * 32 + (lane & 31);
    int kk = tt * 16 + (lane >> 5) * 8;
    const float* srcp = (row < 64) ? (Wl2 + (size_t)row * 256 + kk)
                                   : (Wr2 + (size_t)(row - 64) * 256 + kk);
#pragma unroll
    for (int e = 0; e < 8; ++e) o[e] = f2bf(srcp[e]);
    *reinterpret_cast<int4*>(w2fragG + (size_t)cc * 8) = *reinterpret_cast<int4*>(o);
  }
}

// ---------------- dual-layer scan-based multi-split ----------------
__global__ __launch_bounds__(256) void csr_count(
    const int* __restrict__ dst1, const int* __restrict__ dst2,
    int* __restrict__ H1, int* __restrict__ H2) {
  __shared__ int hist[256];
  int g = blockIdx.x, t = threadIdx.x;
  const int* dst; int* H; int E, nb, chunk;
  if (g < G1) { dst = dst1; H = H1; E = CE1; nb = NBK1; chunk = CHUNK1; }
  else { g -= G1; dst = dst2; H = H2; E = CE2; nb = NBK2; chunk = CHUNK2; }
  hist[t] = 0;
  __syncthreads();
  int e0 = g * chunk, e1 = min(e0 + chunk, E);
  for (int e = e0 + t; e < e1; e += 256) atomicAdd(&hist[dst[e] >> 9], 1);
  __syncthreads();
  if (t < nb) H[g * nb + t] = hist[t];
}

__global__ __launch_bounds__(256) void csr_scan(
    int* __restrict__ H1, int* __restrict__ H2,
    int* __restrict__ T1, int* __restrict__ T2) {
  __shared__ int sm[256];
  int b = blockIdx.x, t = threadIdx.x;
  int* H; int* T; int nb, G;
  if (b < NBK1) { H = H1; T = T1; nb = NBK1; G = G1; }
  else { b -= NBK1; H = H2; T = T2; nb = NBK2; G = G2; }
  int v = (t < G) ? H[t * nb + b] : 0;
  sm[t] = v;
  __syncthreads();
#pragma unroll
  for (int off = 1; off < 256; off <<= 1) {
    int u = (t >= off) ? sm[t - off] : 0;
    __syncthreads();
    sm[t] += u;
    __syncthreads();
  }
  if (t < G) H[t * nb + b] = sm[t] - v;  // exclusive over chunks
  if (t == 255) T[b] = sm[255];          // bucket total
}

__global__ __launch_bounds__(256) void csr_base(
    const int* __restrict__ T1, const int* __restrict__ T2,
    int* __restrict__ Bb1, int* __restrict__ Bb2) {
  __shared__ int sm[256];
  int t = threadIdx.x;
  const int* T; int* Bb; int nb;
  if (blockIdx.x == 0) { T = T1; Bb = Bb1; nb = NBK1; }
  else { T = T2; Bb = Bb2; nb = NBK2; }
  int v = (t < nb) ? T[t] : 0;
  sm[t] = v;
  __syncthreads();
#pragma unroll
  for (int off = 1; off < 256; off <<= 1) {
    int u = (t >= off) ? sm[t - off] : 0;
    __syncthreads();
    sm[t] += u;
    __syncthreads();
  }
  if (t < nb) Bb[t] = sm[t] - v;
}

__global__ __launch_bounds__(256) void csr_place(
    const int* __restrict__ src1, const int* __restrict__ dst1,
    const int* __restrict__ src2, const int* __restrict__ dst2,
    const int* __restrict__ H1, const int* __restrict__ H2,
    const int* __restrict__ Bb1, const int* __restrict__ Bb2,
    uint32_t* __restrict__ pairs1, uint32_t* __restrict__ pairs2) {
  __shared__ int curs[256];
  int g = blockIdx.x, t = threadIdx.x;
  const int* src; const int* dst; const int* H; const int* Bb;
  uint32_t* pairs; int E, nb, chunk;
  if (g < G1) { src = src1; dst = dst1; H = H1; Bb = Bb1; pairs = pairs1;
                E = CE1; nb = NBK1; chunk = CHUNK1; }
  else { g -= G1; src = src2; dst = dst2; H = H2; Bb = Bb2; pairs = pairs2;
         E = CE2; nb = NBK2; chunk = CHUNK2; }
  if (t < nb) curs[t] = Bb[t] + H[g * nb + t];
  __syncthreads();
  int e0 = g * chunk, e1 = min(e0 + chunk, E);
  for (int e = e0 + t; e < e1; e += 256) {
    int d = dst[e];
    int b = d >> 9;
    int p = atomicAdd(&curs[b], 1);
    pairs[p] = (uint32_t)src[e] | ((uint32_t)(d & 511) << 18);
  }
}

__global__ __launch_bounds__(256) void csr_bdeg(
    const uint32_t* __restrict__ pairs1, const uint32_t* __restrict__ pairs2,
    const int* __restrict__ Bb1, const int* __restrict__ Bb2,
    const int* __restrict__ T1, const int* __restrict__ T2,
    int* __restrict__ deg1, int* __restrict__ deg2) {
  __shared__ int cnt[512];
  int b = blockIdx.x, t = threadIdx.x;
  const uint32_t* pairs; const int* Bb; const int* T; int* deg; int ndst;
  if (b < NBK1) { pairs = pairs1; Bb = Bb1; T = T1; deg = deg1; ndst = CN1; }
  else { b -= NBK1; pairs = pairs2; Bb = Bb2; T = T2; deg = deg2; ndst = CN2; }
  cnt[t] = 0;
  cnt[t + 256] = 0;
  __syncthreads();
  int s0 = Bb[b], n = T[b];
  for (int i = t; i < n; i += 256) atomicAdd(&cnt[pairs[s0 + i] >> 18], 1);
  __syncthreads();
  int d0 = b << 9;
#pragma unroll
  for (int j = 0; j < 2; ++j) {
    int dd = d0 + t + j * 256;
    if (dd < ndst) deg[dd] = cnt[t + j * 256];
  }
}

__global__ __launch_bounds__(256) void csr_scan_local(
    const int* __restrict__ deg1, const int* __restrict__ deg2,
    int* __restrict__ R1, int* __restrict__ R2,
    int* __restrict__ part1, int* __restrict__ part2) {
  __shared__ int sm[256];
  int b = blockIdx.x, t = threadIdx.x;
  const int* deg; int* R; int* part; int N;
  if (b < NBK1) { deg = deg1; R = R1; part = part1; N = CN1; }
  else { b -= NBK1; deg = deg2; R = R2; part = part2; N = CN2; }
  int base = b * 512;
  int i0 = base + 2 * t, i1 = base + 2 * t + 1;
  int a = (i0 < N) ? deg[i0] : 0;
  int bb = (i1 < N) ? deg[i1] : 0;
  int s = a + bb;
  sm[t] = s;
  __syncthreads();
#pragma unroll
  for (int off = 1; off < 256; off <<= 1) {
    int v = (t >= off) ? sm[t - off] : 0;
    __syncthreads();
    sm[t] += v;
    __syncthreads();
  }
  int excl = sm[t] - s;
  if (i0 < N) R[i0] = excl;
  if (i1 < N) R[i1] = excl + a;
  if (t == 255) part[b] = sm[255];
}

__global__ __launch_bounds__(256) void csr_scan_part(
    int* __restrict__ part1, int* __restrict__ part2) {
  __shared__ int sm[256];
  int t = threadIdx.x;
  int* part; int B;
  if (blockIdx.x == 0) { part = part1; B = NBK1; }
  else { part = part2; B = NBK2; }
  int v = (t < B) ? part[t] : 0;
  sm[t] = v;
  __syncthreads();
#pragma unroll
  for (int off = 1; off < 256; off <<= 1) {
    int u = (t >= off) ? sm[t - off] : 0;
    __syncthreads();
    sm[t] += u;
    __syncthreads();
  }
  if (t < B) part[t] = sm[t] - v;
}

// bplace with addback folded in: final offset = R[dd] + part[bucket]
__global__ __launch_bounds__(256) void csr_bplace(
    const uint32_t* __restrict__ pairs1, const uint32_t* __restrict__ pairs2,
    const int* __restrict__ Bb1, const int* __restrict__ Bb2,
    const int* __restrict__ T1, const int* __restrict__ T2,
    const int* __restrict__ R1, const int* __restrict__ R2,
    const int* __restrict__ part1, const int* __restrict__ part2,
    int* __restrict__ esrc1, int* __restrict__ esrc2) {
  __shared__ int curs[512];
  int b = blockIdx.x, t = threadIdx.x;
  const uint32_t* pairs; const int* Bb; const int* T; const int* R;
  const int* part; int* esrc; int ndst;
  if (b < NBK1) { pairs = pairs1; Bb = Bb1; T = T1; R = R1; part = part1;
                  esrc = esrc1; ndst = CN1; }
  else { b -= NBK1; pairs = pairs2; Bb = Bb2; T = T2; R = R2; part = part2;
         esrc = esrc2; ndst = CN2; }
  int d0 = b << 9;
  int pb = part[b];
#pragma unroll
  for (int j = 0; j < 2; ++j) {
    int dd = d0 + t + j * 256;
    curs[t + j * 256] = (dd < ndst) ? R[dd] + pb : 0;
  }
  __syncthreads();
  int s0 = Bb[b], n = T[b];
  for (int i = t; i < n; i += 256) {
    uint32_t pk = pairs[s0 + i];
    int p = atomicAdd(&curs[pk >> 18], 1);
    esrc[p] = (int)(pk & 0x3FFFFu);
  }
}

// ------- gather-mean layer 1: 64 lanes/dst, 8-wide unroll (MLP=8) -------
__global__ __launch_bounds__(256) void sage_gather1(
    const uint16_t* __restrict__ xbf, const int* __restrict__ esrc,
    const int* __restrict__ R, const int* __restrict__ part,
    const int* __restrict__ deg, uint16_t* __restrict__ agg) {
  int d = blockIdx.x * 4 + (threadIdx.x >> 6);
  int c = threadIdx.x & 63;
  if (d >= CN1) return;
  int start = R[d] + part[d >> 9], n = deg[d];
  const uint32_t* xw = reinterpret_cast<const uint32_t*>(xbf);
  float a0 = 0.f, a1 = 0.f, b0 = 0.f, b1 = 0.f;
  int i = 0;
  for (; i + 8 <= n; i += 8) {
    int s0 = esrc[start + i + 0], s1 = esrc[start + i + 1];
    int s2 = esrc[start + i + 2], s3 = esrc[start + i + 3];
    int s4 = esrc[start + i + 4], s5 = esrc[start + i + 5];
    int s6 = esrc[start + i + 6], s7 = esrc[start + i + 7];
    uint32_t v0 = xw[(size_t)s0 * 64 + c], v1 = xw[(size_t)s1 * 64 + c];
    uint32_t v2 = xw[(size_t)s2 * 64 + c], v3 = xw[(size_t)s3 * 64 + c];
    uint32_t v4 = xw[(size_t)s4 * 64 + c], v5 = xw[(size_t)s5 * 64 + c];
    uint32_t v6 = xw[(size_t)s6 * 64 + c], v7 = xw[(size_t)s7 * 64 + c];
    a0 += (blo(v0) + blo(v1)) + (blo(v2) + blo(v3));
    b0 += (blo(v4) + blo(v5)) + (blo(v6) + blo(v7));
    a1 += (bhi(v0) + bhi(v1)) + (bhi(v2) + bhi(v3));
    b1 += (bhi(v4) + bhi(v5)) + (bhi(v6) + bhi(v7));
  }
  for (; i + 2 <= n; i += 2) {
    int s0 = esrc[start + i + 0], s1 = esrc[start + i + 1];
    uint32_t v0 = xw[(size_t)s0 * 64 + c], v1 = xw[(size_t)s1 * 64 + c];
    a0 += blo(v0) + blo(v1);
    a1 += bhi(v0) + bhi(v1);
  }
  if (i < n) {
    uint32_t v = xw[(size_t)esrc[start + i] * 64 + c];
    a0 += blo(v);
    a1 += bhi(v);
  }
  a0 += b0; a1 += b1;
  float inv = 1.0f / fmaxf((float)n, 1.0f);
  uint32_t packed = (uint32_t)f2bf(a0 * inv) | ((uint32_t)f2bf(a1 * inv) << 16);
  reinterpret_cast<uint32_t*>(agg)[(size_t)d * 64 + c] = packed;
}

// ------- FUSED gather-mean layer 2 + log_softmax finalize -------
// 32 lanes per dst (half-wave); lane c owns cols {2c, 2c+1}.
// After the mean: v = out[d] + mean + b2; softmax reduce via shfl_xor 16..1
// (stays within each 32-lane half); write log_softmax back to out.
__global__ __launch_bounds__(256) void sage_gather2_fin(
    const uint16_t* __restrict__ t2, const int* __restrict__ esrc,
    const int* __restrict__ R, const int* __restrict__ part,
    const int* __restrict__ deg, const float* __restrict__ b2,
    float* __restrict__ out) {
  int d = blockIdx.x * 8 + (threadIdx.x >> 5);
  int c = threadIdx.x & 31;
  if (d >= CN2) return;
  int start = R[d] + part[d >> 9], n = deg[d];
  const uint32_t* tw = reinterpret_cast<const uint32_t*>(t2);
  float a0 = 0.f, a1 = 0.f, b0 = 0.f, b1 = 0.f;
  int i = 0;
  for (; i + 8 <= n; i += 8) {
    int s0 = esrc[start + i + 0], s1 = esrc[start + i + 1];
    int s2 = esrc[start + i + 2], s3 = esrc[start + i + 3];
    int s4 = esrc[start + i + 4], s5 = esrc[start + i + 5];
    int s6 = esrc[start + i + 6], s7 = esrc[start + i + 7];
    uint32_t v0 = tw[(size_t)s0 * 32 + c], v1 = tw[(size_t)s1 * 32 + c];
    uint32_t v2 = tw[(size_t)s2 * 32 + c], v3 = tw[(size_t)s3 * 32 + c];
    uint32_t v4 = tw[(size_t)s4 * 32 + c], v5 = tw[(size_t)s5 * 32 + c];
    uint32_t v6 = tw[(size_t)s6 * 32 + c], v7 = tw[(size_t)s7 * 32 + c];
    a0 += (blo(v0) + blo(v1)) + (blo(v2) + blo(v3));
    b0 += (blo(v4) + blo(v5)) + (blo(v6) + blo(v7));
    a1 += (bhi(v0) + bhi(v1)) + (bhi(v2) + bhi(v3));
    b1 += (bhi(v4) + bhi(v5)) + (bhi(v6) + bhi(v7));
  }
  for (; i + 2 <= n; i += 2) {
    int s0 = esrc[start + i + 0], s1 = esrc[start + i + 1];
    uint32_t v0 = tw[(size_t)s0 * 32 + c], v1 = tw[(size_t)s1 * 32 + c];
    a0 += blo(v0) + blo(v1);
    a1 += bhi(v0) + bhi(v1);
  }
  if (i < n) {
    uint32_t v = tw[(size_t)esrc[start + i] * 32 + c];
    a0 += blo(v);
    a1 += bhi(v);
  }
  a0 += b0; a1 += b1;
  float inv = 1.0f / fmaxf((float)n, 1.0f);

  float2 ov = reinterpret_cast<const float2*>(out)[(size_t)d * 32 + c];
  float2 bb = reinterpret_cast<const float2*>(b2)[c];
  float v0 = ov.x + a0 * inv + bb.x;
  float v1 = ov.y + a1 * inv + bb.y;
  float m = fmaxf(v0, v1);
#pragma unroll
  for (int off = 16; off > 0; off >>= 1) m = fmaxf(m, __shfl_xor(m, off));
  float s = expf(v0 - m) + expf(v1 - m);
#pragma unroll
  for (int off = 16; off > 0; off >>= 1) s += __shfl_xor(s, off);
  float lg = logf(s);
  float2 r;
  r.x = v0 - m - lg;
  r.y = v1 - m - lg;
  reinterpret_cast<float2*>(out)[(size_t)d * 32 + c] = r;
}

// ---------------- MEGA kernel (R12: LDS-staged fragment-order W) ----------------
// Each wave owns 32 rows (782 blocks x 4 waves). W1 staged in two 64 KB halves,
// w2 staged once (reusing the same buffer). All B-frag reads are contiguous
// conflict-free ds_read_b128. h1 A-frags (a2[16]) kept in registers.
__global__ __launch_bounds__(256, 2) void sage_mega(
    const uint16_t* __restrict__ agg, const uint16_t* __restrict__ xbf,
    const uint16_t* __restrict__ wfragG, const uint16_t* __restrict__ w2fragG,
    const float* __restrict__ bias, uint16_t* __restrict__ t2,
    float* __restrict__ outp) {
  __shared__ uint16_t wfrag[32768];       // 64 KB: 64 chunks x 512 shorts
  __shared__ uint16_t h1t[4 * 32 * 40];   // 10240 B; per-wave 32x40 transpose tile
  const int tid = threadIdx.x;
  const int w = tid >> 6;
  const int lane = tid & 63;
  const int lcol = lane & 31;             // A-row / B-col / C-col
  const int hi = lane >> 5;               // k-half (frags) / row +4 (C)
  const int row0 = blockIdx.x * 128 + w * 32;
  uint16_t* hw = &h1t[w * (32 * 40)];

  // A fragments: 16 k-tiles of K=16 from [agg | x]; lane: row=lcol, k=hi*8..+7
  int arow = row0 + lcol;
  arow = arow < CN1 ? arow : CN1 - 1;
  bf16x8 afr[16];
#pragma unroll
  for (int t = 0; t < 16; ++t) {
    const uint16_t* Asrc = (t < 8) ? agg : xbf;
    const int koff = (t < 8) ? t * 16 : t * 16 - 128;
    afr[t] = *reinterpret_cast<const bf16x8*>(
        Asrc + (size_t)arow * CD_IN + koff + hi * 8);
  }

  const bool do_out = (row0 < CN2);       // CN2 % 32 == 0 -> wave-uniform
  bf16x8 a2[16];                          // h1 A-frags, filled per n (static idx)

#pragma unroll
  for (int h = 0; h < 2; ++h) {
    // stage half h of W1 fragments: 64 chunks x 1 KB, 16 per wave, coalesced
#pragma unroll
    for (int i = 0; i < 16; ++i) {
      int cc = i * 4 + w;
      int4 v = *reinterpret_cast<const int4*>(
          wfragG + (size_t)(h * 64 + cc) * 512 + lane * 8);
      *reinterpret_cast<int4*>(&wfrag[cc * 512 + lane * 8]) = v;
    }
    __syncthreads();
#pragma unroll
    for (int nn = 0; nn < 4; ++nn) {
      const int n = h * 4 + nn;
      const float bb = bias[n * 32 + lcol];
      f32x16 p0 = (f32x16)0.0f, p1 = (f32x16)0.0f;
#pragma unroll
      for (int t = 0; t < 16; t += 2) {
        bf16x8 b0 = *reinterpret_cast<const bf16x8*>(
            &wfrag[((nn * 16 + t) * 64 + lane) * 8]);
        bf16x8 b1 = *reinterpret_cast<const bf16x8*>(
            &wfrag[((nn * 16 + t + 1) * 64 + lane) * 8]);
        p0 = __builtin_amdgcn_mfma_f32_32x32x16_bf16(afr[t], b0, p0, 0, 0, 0);
        p1 = __builtin_amdgcn_mfma_f32_32x32x16_bf16(afr[t + 1], b1, p1, 0, 0, 0);
      }
      // bias + relu -> bf16 -> per-wave LDS transpose tile (C layout m74/m101)
#pragma unroll
      for (int r = 0; r < 16; ++r) {
        float v = fmaxf(p0[r] + p1[r] + bb, 0.0f);
        int R = (r & 3) + 8 * (r >> 2) + 4 * hi;
        hw[R * 40 + lcol] = f2bf(v);
      }
      // read back as phase-2 A-frags (k = n*32 + {0..15, 16..31})
      a2[n * 2 + 0] = *reinterpret_cast<const bf16x8*>(&hw[lcol * 40 + hi * 8]);
      a2[n * 2 + 1] = *reinterpret_cast<const bf16x8*>(&hw[lcol * 40 + 16 + hi * 8]);
    }
    __syncthreads();   // all waves done reading this half before overwrite
  }

  // stage w2 fragments (64 KB) into the same buffer
#pragma unroll
  for (int i = 0; i < 16; ++i) {
    int cc = i * 4 + w;
    int4 v = *reinterpret_cast<const int4*>(
        w2fragG + (size_t)cc * 512 + lane * 8);
    *reinterpret_cast<int4*>(&wfrag[cc * 512 + lane * 8]) = v;
  }
  __syncthreads();

  // ---- phase 2: jp=0 -> t2 cols (j=0,1); jp=1 -> out cols (j=2,3) ----
#pragma unroll
  for (int jp = 0; jp < 2; ++jp) {
    if (jp == 1 && !do_out) break;
    const int jA = jp * 2, jB = jp * 2 + 1;
    f32x16 aA = (f32x16)0.0f, aB = (f32x16)0.0f;
#pragma unroll
    for (int s = 0; s < 8; ++s) {
      bf16x8 c0A = *reinterpret_cast<const bf16x8*>(
          &wfrag[((jA * 16 + s * 2) * 64 + lane) * 8]);
      bf16x8 c1A = *reinterpret_cast<const bf16x8*>(
          &wfrag[((jA * 16 + s * 2 + 1) * 64 + lane) * 8]);
      bf16x8 c0B = *reinterpret_cast<const bf16x8*>(
          &wfrag[((jB * 16 + s * 2) * 64 + lane) * 8]);
      bf16x8 c1B = *reinterpret_cast<const bf16x8*>(
          &wfrag[((jB * 16 + s * 2 + 1) * 64 + lane) * 8]);
      aA = __builtin_amdgcn_mfma_f32_32x32x16_bf16(a2[s * 2], c0A, aA, 0, 0, 0);
      aB = __builtin_amdgcn_mfma_f32_32x32x16_bf16(a2[s * 2], c0B, aB, 0, 0, 0);
      aA = __builtin_amdgcn_mfma_f32_32x32x16_bf16(a2[s * 2 + 1], c1A, aA, 0, 0, 0);
      aB = __builtin_amdgcn_mfma_f32_32x32x16_bf16(a2[s * 2 + 1], c1B, aB, 0, 0, 0);
    }
    if (jp == 0) {
#pragma unroll
      for (int r = 0; r < 16; ++r) {
        int R = (r & 3) + 8 * (r >> 2) + 4 * hi;
        int rg = row0 + R;
        if (rg < CN1) {
          t2[(size_t)rg * 64 + lcol] = f2bf(aA[r]);
          t2[(size_t)rg * 64 + 32 + lcol] = f2bf(aB[r]);
        }
      }
    } else {
#pragma unroll
      for (int r = 0; r < 16; ++r) {
        int R = (r & 3) + 8 * (r >> 2) + 4 * hi;
        int rg = row0 + R;
        outp[(size_t)rg * 64 + lcol] = aA[r];
        outp[(size_t)rg * 64 + 32 + lcol] = aB[r];
      }
    }
  }
}

extern "C" void kernel_launch(void* const* d_in, const int* in_sizes, int n_in,
                              void* d_out, int out_size, void* d_ws, size_t ws_size,
                              hipStream_t stream) {
  const float* x    = (const float*)d_in[0];
  const int* src1   = (const int*)d_in[1];
  const int* dst1   = (const int*)d_in[2];
  const int* src2   = (const int*)d_in[3];
  const int* dst2   = (const int*)d_in[4];
  const float* W_l1 = (const float*)d_in[5];
  const float* b_l1 = (const float*)d_in[6];
  const float* W_r1 = (const float*)d_in[7];
  const float* W_l2 = (const float*)d_in[8];
  const float* b_l2 = (const float*)d_in[9];
  const float* W_r2 = (const float*)d_in[10];
  float* out = (float*)d_out;
  char* base = (char*)d_ws;

  // ---- workspace layout (bytes), ~111.5 MB ----
  uint16_t* x_bf  = (uint16_t*)base;                       // 51.2 MB
  uint16_t* t2_bf = (uint16_t*)(base + 51200000);          // 12.8 MB
  uint32_t* pairs1= (uint32_t*)(base + 64000000);          // 6.4 MB (E1*4)
  uint32_t* pairs2= (uint32_t*)(base + 70400000);          // 1.28 MB (E2*4)
  uint16_t* agg_bf= (uint16_t*)(base + 71680000);          // 25.6 MB
  int* deg1 = (int*)(base + 102400000);                    // 400 KB
  int* R1   = (int*)(base + 102800000);                    // 400 KB
  int* esrc1= (int*)(base + 103200000);                    // 6.4 MB
  int* deg2 = (int*)(base + 109600000);                    // 80 KB
  int* R2   = (int*)(base + 109680000);                    // 80 KB
  int* esrc2= (int*)(base + 109760000);                    // 1.28 MB
  int* H1   = (int*)(base + 111040000);                    // 200,704 B
  int* H2   = (int*)(base + 111240704);                    // 10,240 B
  char* misc = base + 111250944;
  int* T1  = (int*)(misc);
  int* Bb1 = (int*)(misc + 1024);
  int* T2  = (int*)(misc + 2048);
  int* Bb2 = (int*)(misc + 3072);
  int* part1 = (int*)(misc + 4096);
  int* part2 = (int*)(misc + 5120);
  uint16_t* wfragG  = (uint16_t*)(misc + 6144);            // 128 KB (frag order)
  uint16_t* w2fragG = wfragG + 65536;                      // 64 KB (frag order)

  if (ws_size < 112000000u) return;

  // ---- fused converts ----
  cvt_all<<<25048, 256, 0, stream>>>(x, W_l1, W_r1, W_l2, W_r2,
                                     x_bf, wfragG, w2fragG);

  // ---- dual-layer CSR build ----
  csr_count<<<G1 + G2, 256, 0, stream>>>(dst1, dst2, H1, H2);
  csr_scan<<<NBK1 + NBK2, 256, 0, stream>>>(H1, H2, T1, T2);
  csr_base<<<2, 256, 0, stream>>>(T1, T2, Bb1, Bb2);
  csr_place<<<G1 + G2, 256, 0, stream>>>(src1, dst1, src2, dst2, H1, H2,
                                         Bb1, Bb2, pairs1, pairs2);
  csr_bdeg<<<NBK1 + NBK2, 256, 0, stream>>>(pairs1, pairs2, Bb1, Bb2, T1, T2,
                                            deg1, deg2);
  csr_scan_local<<<NBK1 + NBK2, 256, 0, stream>>>(deg1, deg2, R1, R2, part1, part2);
  csr_scan_part<<<2, 256, 0, stream>>>(part1, part2);
  csr_bplace<<<NBK1 + NBK2, 256, 0, stream>>>(pairs1, pairs2, Bb1, Bb2, T1, T2,
                                              R1, R2, part1, part2, esrc1, esrc2);

  // ---- gather1 -> mega -> fused gather2+finalize ----
  sage_gather1<<<(CN1 + 3) / 4, 256, 0, stream>>>(x_bf, esrc1, R1, part1, deg1, agg_bf);
  sage_mega<<<(CN1 + 127) / 128, 256, 0, stream>>>(
      agg_bf, x_bf, wfragG, w2fragG, b_l1, t2_bf, out);
  sage_gather2_fin<<<(CN2 + 7) / 8, 256, 0, stream>>>(
      t2_bf, esrc2, R2, part2, deg2, b_l2, out);
}

// Round 14
// 191.881 us; speedup vs baseline: 1.6909x; 1.0221x over previous
//
#include <hip/hip_runtime.h>
#include <stdint.h>

// SAGE_876173328847: 2-layer bipartite SAGEConv (mean agg) + log_softmax.
// N0=200000, N1=100000, N2=20000, E1=1.6M, E2=320K, D_IN=128, D_H=256, D_OUT=64.
//
// R1: atomic scatter -> CSR build + gather (3309 -> 667 us).
// R2/R3: bf16 heavy path + MFMA GEMMs (667 -> 547 us).
// R4: fused mega-kernel, h1 lives only in LDS (547 -> 472 us).
// R7: scan-based multi-split CSR build, zero global atomics (-> 366 us).
// R8: spill-free mega (-> 347). R9: launch fusion 22->14 (-> 285).
// R11: 32x32x16 MFMA 32-rows/wave fused mega (-> 264).
// R12: fragment-order W + LDS staging (-> 212). R13: gather1 MLP=8 + fused
//      gather2+finalize + fused converts (-> 196).
// R14: gather1 VALU/byte cut ~2x: one dst per WAVE (scalar edge-index loads
//      via readfirstlane), uint2 row loads with 32-bit offsets, even/odd
//      edges split across half-waves + shfl_xor(32) combine. csr_count
//      fused into cvt_all. 12 -> 11 dispatches.

#define CN0 200000
#define CN1 100000
#define CN2 20000
#define CE1 1600000
#define CE2 320000
#define CD_IN 128
#define CD_H 256
#define CD_OUT 64

// multi-split geometry: bucket = dst >> 9 (512 dsts per bucket)
#define NBK1 196          // ceil(N1/512)
#define NBK2 40           // ceil(N2/512)
#define G1 256
#define G2 64
#define CHUNK1 6250       // E1 / G1
#define CHUNK2 5000       // E2 / G2

typedef __bf16 bf16x8 __attribute__((ext_vector_type(8)));
typedef float f32x4 __attribute__((ext_vector_type(4)));
typedef float f32x16 __attribute__((ext_vector_type(16)));
typedef uint16_t u16x4 __attribute__((ext_vector_type(4)));

__device__ inline uint16_t f2bf(float f) {
  uint32_t u = __float_as_uint(f);
  return (uint16_t)((u + 0x7fffu + ((u >> 16) & 1u)) >> 16);
}
__device__ inline float blo(uint32_t v) { return __uint_as_float(v << 16); }
__device__ inline float bhi(uint32_t v) { return __uint_as_float(v & 0xffff0000u); }

// ---- fused: x convert (25000 blk) + weight frags (48 blk) + csr_count (320 blk) ----
// wfragG : [8 n][16 t][64 lane][8] ; value = Wcat[n*32+(lane&31)][t*16+(lane>>5)*8+e]
// w2fragG: [4 j][16 tt][64 lane][8]; value = W2cat[j*32+(lane&31)][tt*16+(lane>>5)*8+e]
__global__ __launch_bounds__(256) void cvt_count(
    const float* __restrict__ x, const float* __restrict__ Wl1,
    const float* __restrict__ Wr1, const float* __restrict__ Wl2,
    const float* __restrict__ Wr2, const int* __restrict__ dst1,
    const int* __restrict__ dst2, uint16_t* __restrict__ x_bf,
    uint16_t* __restrict__ wfragG, uint16_t* __restrict__ w2fragG,
    int* __restrict__ H1, int* __restrict__ H2) {
  __shared__ int hist[256];
  int blk = blockIdx.x;
  if (blk < 25000) {
    int i = blk * 256 + threadIdx.x;      // < 6,400,000 exactly
    float4 v = reinterpret_cast<const float4*>(x)[i];
    u16x4 o = {f2bf(v.x), f2bf(v.y), f2bf(v.z), f2bf(v.w)};
    reinterpret_cast<u16x4*>(x_bf)[i] = o;
    return;
  }
  if (blk < 25048) {
    int c = (blk - 25000) * 256 + threadIdx.x;   // 0..12287
    uint16_t o[8];
    if (c < 8192) {
      int lane = c & 63, t = (c >> 6) & 15, n = c >> 10;
      int row = n * 32 + (lane & 31);
      int kk = t * 16 + (lane >> 5) * 8;
      const float* srcp = (kk < 128) ? (Wl1 + (size_t)row * 128 + kk)
                                     : (Wr1 + (size_t)row * 128 + (kk - 128));
#pragma unroll
      for (int e = 0; e < 8; ++e) o[e] = f2bf(srcp[e]);
      *reinterpret_cast<int4*>(wfragG + (size_t)c * 8) = *reinterpret_cast<int4*>(o);
    } else {
      int cc = c - 8192;                    // 0..4095
      int lane = cc & 63, tt = (cc >> 6) & 15, j = cc >> 10;
      int row = j * 32 + (lane & 31);
      int kk = tt * 16 + (lane >> 5) * 8;
      const float* srcp = (row < 64) ? (Wl2 + (size_t)row * 256 + kk)
                                     : (Wr2 + (size_t)(row - 64) * 256 + kk);
#pragma unroll
      for (int e = 0; e < 8; ++e) o[e] = f2bf(srcp[e]);
      *reinterpret_cast<int4*>(w2fragG + (size_t)cc * 8) = *reinterpret_cast<int4*>(o);
    }
    return;
  }
  // ---- histogram chunk ----
  int g = blk - 25048, t = threadIdx.x;
  const int* dst; int* H; int E, nb, chunk;
  if (g < G1) { dst = dst1; H = H1; E = CE1; nb = NBK1; chunk = CHUNK1; }
  else { g -= G1; dst = dst2; H = H2; E = CE2; nb = NBK2; chunk = CHUNK2; }
  hist[t] = 0;
  __syncthreads();
  int e0 = g * chunk, e1 = min(e0 + chunk, E);
  for (int e = e0 + t; e < e1; e += 256) atomicAdd(&hist[dst[e] >> 9], 1);
  __syncthreads();
  if (t < nb) H[g * nb + t] = hist[t];
}

// ---------------- dual-layer scan-based multi-split ----------------
__global__ __launch_bounds__(256) void csr_scan(
    int* __restrict__ H1, int* __restrict__ H2,
    int* __restrict__ T1, int* __restrict__ T2) {
  __shared__ int sm[256];
  int b = blockIdx.x, t = threadIdx.x;
  int* H; int* T; int nb, G;
  if (b < NBK1) { H = H1; T = T1; nb = NBK1; G = G1; }
  else { b -= NBK1; H = H2; T = T2; nb = NBK2; G = G2; }
  int v = (t < G) ? H[t * nb + b] : 0;
  sm[t] = v;
  __syncthreads();
#pragma unroll
  for (int off = 1; off < 256; off <<= 1) {
    int u = (t >= off) ? sm[t - off] : 0;
    __syncthreads();
    sm[t] += u;
    __syncthreads();
  }
  if (t < G) H[t * nb + b] = sm[t] - v;  // exclusive over chunks
  if (t == 255) T[b] = sm[255];          // bucket total
}

__global__ __launch_bounds__(256) void csr_base(
    const int* __restrict__ T1, const int* __restrict__ T2,
    int* __restrict__ Bb1, int* __restrict__ Bb2) {
  __shared__ int sm[256];
  int t = threadIdx.x;
  const int* T; int* Bb; int nb;
  if (blockIdx.x == 0) { T = T1; Bb = Bb1; nb = NBK1; }
  else { T = T2; Bb = Bb2; nb = NBK2; }
  int v = (t < nb) ? T[t] : 0;
  sm[t] = v;
  __syncthreads();
#pragma unroll
  for (int off = 1; off < 256; off <<= 1) {
    int u = (t >= off) ? sm[t - off] : 0;
    __syncthreads();
    sm[t] += u;
    __syncthreads();
  }
  if (t < nb) Bb[t] = sm[t] - v;
}

__global__ __launch_bounds__(256) void csr_place(
    const int* __restrict__ src1, const int* __restrict__ dst1,
    const int* __restrict__ src2, const int* __restrict__ dst2,
    const int* __restrict__ H1, const int* __restrict__ H2,
    const int* __restrict__ Bb1, const int* __restrict__ Bb2,
    uint32_t* __restrict__ pairs1, uint32_t* __restrict__ pairs2) {
  __shared__ int curs[256];
  int g = blockIdx.x, t = threadIdx.x;
  const int* src; const int* dst; const int* H; const int* Bb;
  uint32_t* pairs; int E, nb, chunk;
  if (g < G1) { src = src1; dst = dst1; H = H1; Bb = Bb1; pairs = pairs1;
                E = CE1; nb = NBK1; chunk = CHUNK1; }
  else { g -= G1; src = src2; dst = dst2; H = H2; Bb = Bb2; pairs = pairs2;
         E = CE2; nb = NBK2; chunk = CHUNK2; }
  if (t < nb) curs[t] = Bb[t] + H[g * nb + t];
  __syncthreads();
  int e0 = g * chunk, e1 = min(e0 + chunk, E);
  for (int e = e0 + t; e < e1; e += 256) {
    int d = dst[e];
    int b = d >> 9;
    int p = atomicAdd(&curs[b], 1);
    pairs[p] = (uint32_t)src[e] | ((uint32_t)(d & 511) << 18);
  }
}

__global__ __launch_bounds__(256) void csr_bdeg(
    const uint32_t* __restrict__ pairs1, const uint32_t* __restrict__ pairs2,
    const int* __restrict__ Bb1, const int* __restrict__ Bb2,
    const int* __restrict__ T1, const int* __restrict__ T2,
    int* __restrict__ deg1, int* __restrict__ deg2) {
  __shared__ int cnt[512];
  int b = blockIdx.x, t = threadIdx.x;
  const uint32_t* pairs; const int* Bb; const int* T; int* deg; int ndst;
  if (b < NBK1) { pairs = pairs1; Bb = Bb1; T = T1; deg = deg1; ndst = CN1; }
  else { b -= NBK1; pairs = pairs2; Bb = Bb2; T = T2; deg = deg2; ndst = CN2; }
  cnt[t] = 0;
  cnt[t + 256] = 0;
  __syncthreads();
  int s0 = Bb[b], n = T[b];
  for (int i = t; i < n; i += 256) atomicAdd(&cnt[pairs[s0 + i] >> 18], 1);
  __syncthreads();
  int d0 = b << 9;
#pragma unroll
  for (int j = 0; j < 2; ++j) {
    int dd = d0 + t + j * 256;
    if (dd < ndst) deg[dd] = cnt[t + j * 256];
  }
}

__global__ __launch_bounds__(256) void csr_scan_local(
    const int* __restrict__ deg1, const int* __restrict__ deg2,
    int* __restrict__ R1, int* __restrict__ R2,
    int* __restrict__ part1, int* __restrict__ part2) {
  __shared__ int sm[256];
  int b = blockIdx.x, t = threadIdx.x;
  const int* deg; int* R; int* part; int N;
  if (b < NBK1) { deg = deg1; R = R1; part = part1; N = CN1; }
  else { b -= NBK1; deg = deg2; R = R2; part = part2; N = CN2; }
  int base = b * 512;
  int i0 = base + 2 * t, i1 = base + 2 * t + 1;
  int a = (i0 < N) ? deg[i0] : 0;
  int bb = (i1 < N) ? deg[i1] : 0;
  int s = a + bb;
  sm[t] = s;
  __syncthreads();
#pragma unroll
  for (int off = 1; off < 256; off <<= 1) {
    int v = (t >= off) ? sm[t - off] : 0;
    __syncthreads();
    sm[t] += v;
    __syncthreads();
  }
  int excl = sm[t] - s;
  if (i0 < N) R[i0] = excl;
  if (i1 < N) R[i1] = excl + a;
  if (t == 255) part[b] = sm[255];
}

__global__ __launch_bounds__(256) void csr_scan_part(
    int* __restrict__ part1, int* __restrict__ part2) {
  __shared__ int sm[256];
  int t = threadIdx.x;
  int* part; int B;
  if (blockIdx.x == 0) { part = part1; B = NBK1; }
  else { part = part2; B = NBK2; }
  int v = (t < B) ? part[t] : 0;
  sm[t] = v;
  __syncthreads();
#pragma unroll
  for (int off = 1; off < 256; off <<= 1) {
    int u = (t >= off) ? sm[t - off] : 0;
    __syncthreads();
    sm[t] += u;
    __syncthreads();
  }
  if (t < B) part[t] = sm[t] - v;
}

// bplace with addback folded in: final offset = R[dd] + part[bucket]
__global__ __launch_bounds__(256) void csr_bplace(
    const uint32_t* __restrict__ pairs1, const uint32_t* __restrict__ pairs2,
    const int* __restrict__ Bb1, const int* __restrict__ Bb2,
    const int* __restrict__ T1, const int* __restrict__ T2,
    const int* __restrict__ R1, const int* __restrict__ R2,
    const int* __restrict__ part1, const int* __restrict__ part2,
    int* __restrict__ esrc1, int* __restrict__ esrc2) {
  __shared__ int curs[512];
  int b = blockIdx.x, t = threadIdx.x;
  const uint32_t* pairs; const int* Bb; const int* T; const int* R;
  const int* part; int* esrc; int ndst;
  if (b < NBK1) { pairs = pairs1; Bb = Bb1; T = T1; R = R1; part = part1;
                  esrc = esrc1; ndst = CN1; }
  else { b -= NBK1; pairs = pairs2; Bb = Bb2; T = T2; R = R2; part = part2;
         esrc = esrc2; ndst = CN2; }
  int d0 = b << 9;
  int pb = part[b];
#pragma unroll
  for (int j = 0; j < 2; ++j) {
    int dd = d0 + t + j * 256;
    curs[t + j * 256] = (dd < ndst) ? R[dd] + pb : 0;
  }
  __syncthreads();
  int s0 = Bb[b], n = T[b];
  for (int i = t; i < n; i += 256) {
    uint32_t pk = pairs[s0 + i];
    int p = atomicAdd(&curs[pk >> 18], 1);
    esrc[p] = (int)(pk & 0x3FFFFu);
  }
}

// ------- gather-mean layer 1 (R14): one dst per WAVE, scalar edge indices,
// uint2 row loads, even/odd edges split across half-waves -------
__global__ __launch_bounds__(256) void sage_gather1(
    const uint16_t* __restrict__ xbf, const int* __restrict__ esrc,
    const int* __restrict__ R, const int* __restrict__ part,
    const int* __restrict__ deg, uint16_t* __restrict__ agg) {
  const int d = __builtin_amdgcn_readfirstlane(blockIdx.x * 4 + (threadIdx.x >> 6));
  const int lane = threadIdx.x & 63;
  const int cc = lane & 31;    // uint2 chunk within row (cols 4cc..4cc+3)
  const int h = lane >> 5;     // 0: even edges, 1: odd edges
  const int start = __builtin_amdgcn_readfirstlane(R[d] + part[d >> 9]);
  const int n = __builtin_amdgcn_readfirstlane(deg[d]);
  const uint2* xw = reinterpret_cast<const uint2*>(xbf);
  float f0 = 0.f, f1 = 0.f, f2 = 0.f, f3 = 0.f;
  float g0 = 0.f, g1 = 0.f, g2 = 0.f, g3 = 0.f;
  int i = 0;
  for (; i + 8 <= n; i += 8) {
    int sa = esrc[start + i + 0], sb = esrc[start + i + 1];
    int sc = esrc[start + i + 2], sd = esrc[start + i + 3];
    int se = esrc[start + i + 4], sf = esrc[start + i + 5];
    int sg = esrc[start + i + 6], sh = esrc[start + i + 7];
    uint32_t o0 = (uint32_t)(h ? sb : sa) * 32u + cc;
    uint32_t o1 = (uint32_t)(h ? sd : sc) * 32u + cc;
    uint32_t o2 = (uint32_t)(h ? sf : se) * 32u + cc;
    uint32_t o3 = (uint32_t)(h ? sh : sg) * 32u + cc;
    uint2 v0 = xw[o0];
    uint2 v1 = xw[o1];
    uint2 v2 = xw[o2];
    uint2 v3 = xw[o3];
    f0 += blo(v0.x) + blo(v1.x); f1 += bhi(v0.x) + bhi(v1.x);
    f2 += blo(v0.y) + blo(v1.y); f3 += bhi(v0.y) + bhi(v1.y);
    g0 += blo(v2.x) + blo(v3.x); g1 += bhi(v2.x) + bhi(v3.x);
    g2 += blo(v2.y) + blo(v3.y); g3 += bhi(v2.y) + bhi(v3.y);
  }
  for (; i + 2 <= n; i += 2) {
    int sa = esrc[start + i], sb = esrc[start + i + 1];
    uint2 v = xw[(uint32_t)(h ? sb : sa) * 32u + cc];
    f0 += blo(v.x); f1 += bhi(v.x); f2 += blo(v.y); f3 += bhi(v.y);
  }
  if (i < n) {
    int sa = esrc[start + i];
    uint2 v = xw[(uint32_t)sa * 32u + cc];
    if (h == 0) { f0 += blo(v.x); f1 += bhi(v.x); f2 += blo(v.y); f3 += bhi(v.y); }
  }
  f0 += g0; f1 += g1; f2 += g2; f3 += g3;
  f0 += __shfl_xor(f0, 32);
  f1 += __shfl_xor(f1, 32);
  f2 += __shfl_xor(f2, 32);
  f3 += __shfl_xor(f3, 32);
  if (h == 0) {
    float inv = 1.0f / fmaxf((float)n, 1.0f);
    uint2 o;
    o.x = (uint32_t)f2bf(f0 * inv) | ((uint32_t)f2bf(f1 * inv) << 16);
    o.y = (uint32_t)f2bf(f2 * inv) | ((uint32_t)f2bf(f3 * inv) << 16);
    reinterpret_cast<uint2*>(agg)[(size_t)d * 32 + cc] = o;
  }
}

// ------- FUSED gather-mean layer 2 + log_softmax finalize -------
__global__ __launch_bounds__(256) void sage_gather2_fin(
    const uint16_t* __restrict__ t2, const int* __restrict__ esrc,
    const int* __restrict__ R, const int* __restrict__ part,
    const int* __restrict__ deg, const float* __restrict__ b2,
    float* __restrict__ out) {
  int d = blockIdx.x * 8 + (threadIdx.x >> 5);
  int c = threadIdx.x & 31;
  if (d >= CN2) return;
  int start = R[d] + part[d >> 9], n = deg[d];
  const uint32_t* tw = reinterpret_cast<const uint32_t*>(t2);
  float a0 = 0.f, a1 = 0.f, b0 = 0.f, b1 = 0.f;
  int i = 0;
  for (; i + 8 <= n; i += 8) {
    int s0 = esrc[start + i + 0], s1 = esrc[start + i + 1];
    int s2 = esrc[start + i + 2], s3 = esrc[start + i + 3];
    int s4 = esrc[start + i + 4], s5 = esrc[start + i + 5];
    int s6 = esrc[start + i + 6], s7 = esrc[start + i + 7];
    uint32_t v0 = tw[(size_t)s0 * 32 + c], v1 = tw[(size_t)s1 * 32 + c];
    uint32_t v2 = tw[(size_t)s2 * 32 + c], v3 = tw[(size_t)s3 * 32 + c];
    uint32_t v4 = tw[(size_t)s4 * 32 + c], v5 = tw[(size_t)s5 * 32 + c];
    uint32_t v6 = tw[(size_t)s6 * 32 + c], v7 = tw[(size_t)s7 * 32 + c];
    a0 += (blo(v0) + blo(v1)) + (blo(v2) + blo(v3));
    b0 += (blo(v4) + blo(v5)) + (blo(v6) + blo(v7));
    a1 += (bhi(v0) + bhi(v1)) + (bhi(v2) + bhi(v3));
    b1 += (bhi(v4) + bhi(v5)) + (bhi(v6) + bhi(v7));
  }
  for (; i + 2 <= n; i += 2) {
    int s0 = esrc[start + i + 0], s1 = esrc[start + i + 1];
    uint32_t v0 = tw[(size_t)s0 * 32 + c], v1 = tw[(size_t)s1 * 32 + c];
    a0 += blo(v0) + blo(v1);
    a1 += bhi(v0) + bhi(v1);
  }
  if (i < n) {
    uint32_t v = tw[(size_t)esrc[start + i] * 32 + c];
    a0 += blo(v);
    a1 += bhi(v);
  }
  a0 += b0; a1 += b1;
  float inv = 1.0f / fmaxf((float)n, 1.0f);

  float2 ov = reinterpret_cast<const float2*>(out)[(size_t)d * 32 + c];
  float2 bb = reinterpret_cast<const float2*>(b2)[c];
  float v0 = ov.x + a0 * inv + bb.x;
  float v1 = ov.y + a1 * inv + bb.y;
  float m = fmaxf(v0, v1);
#pragma unroll
  for (int off = 16; off > 0; off >>= 1) m = fmaxf(m, __shfl_xor(m, off));
  float s = expf(v0 - m) + expf(v1 - m);
#pragma unroll
  for (int off = 16; off > 0; off >>= 1) s += __shfl_xor(s, off);
  float lg = logf(s);
  float2 r;
  r.x = v0 - m - lg;
  r.y = v1 - m - lg;
  reinterpret_cast<float2*>(out)[(size_t)d * 32 + c] = r;
}

// ---------------- MEGA kernel (R12: LDS-staged fragment-order W) ----------------
__global__ __launch_bounds__(256, 2) void sage_mega(
    const uint16_t* __restrict__ agg, const uint16_t* __restrict__ xbf,
    const uint16_t* __restrict__ wfragG, const uint16_t* __restrict__ w2fragG,
    const float* __restrict__ bias, uint16_t* __restrict__ t2,
    float* __restrict__ outp) {
  __shared__ uint16_t wfrag[32768];       // 64 KB: 64 chunks x 512 shorts
  __shared__ uint16_t h1t[4 * 32 * 40];   // 10240 B; per-wave 32x40 transpose tile
  const int tid = threadIdx.x;
  const int w = tid >> 6;
  const int lane = tid & 63;
  const int lcol = lane & 31;             // A-row / B-col / C-col
  const int hi = lane >> 5;               // k-half (frags) / row +4 (C)
  const int row0 = blockIdx.x * 128 + w * 32;
  uint16_t* hw = &h1t[w * (32 * 40)];

  // A fragments: 16 k-tiles of K=16 from [agg | x]; lane: row=lcol, k=hi*8..+7
  int arow = row0 + lcol;
  arow = arow < CN1 ? arow : CN1 - 1;
  bf16x8 afr[16];
#pragma unroll
  for (int t = 0; t < 16; ++t) {
    const uint16_t* Asrc = (t < 8) ? agg : xbf;
    const int koff = (t < 8) ? t * 16 : t * 16 - 128;
    afr[t] = *reinterpret_cast<const bf16x8*>(
        Asrc + (size_t)arow * CD_IN + koff + hi * 8);
  }

  const bool do_out = (row0 < CN2);       // CN2 % 32 == 0 -> wave-uniform
  bf16x8 a2[16];                          // h1 A-frags, filled per n (static idx)

#pragma unroll
  for (int h = 0; h < 2; ++h) {
    // stage half h of W1 fragments: 64 chunks x 1 KB, 16 per wave, coalesced
#pragma unroll
    for (int i = 0; i < 16; ++i) {
      int cc = i * 4 + w;
      int4 v = *reinterpret_cast<const int4*>(
          wfragG + (size_t)(h * 64 + cc) * 512 + lane * 8);
      *reinterpret_cast<int4*>(&wfrag[cc * 512 + lane * 8]) = v;
    }
    __syncthreads();
#pragma unroll
    for (int nn = 0; nn < 4; ++nn) {
      const int n = h * 4 + nn;
      const float bb = bias[n * 32 + lcol];
      f32x16 p0 = (f32x16)0.0f, p1 = (f32x16)0.0f;
#pragma unroll
      for (int t = 0; t < 16; t += 2) {
        bf16x8 b0 = *reinterpret_cast<const bf16x8*>(
            &wfrag[((nn * 16 + t) * 64 + lane) * 8]);
        bf16x8 b1 = *reinterpret_cast<const bf16x8*>(
            &wfrag[((nn * 16 + t + 1) * 64 + lane) * 8]);
        p0 = __builtin_amdgcn_mfma_f32_32x32x16_bf16(afr[t], b0, p0, 0, 0, 0);
        p1 = __builtin_amdgcn_mfma_f32_32x32x16_bf16(afr[t + 1], b1, p1, 0, 0, 0);
      }
      // bias + relu -> bf16 -> per-wave LDS transpose tile (C layout m74/m101)
#pragma unroll
      for (int r = 0; r < 16; ++r) {
        float v = fmaxf(p0[r] + p1[r] + bb, 0.0f);
        int R = (r & 3) + 8 * (r >> 2) + 4 * hi;
        hw[R * 40 + lcol] = f2bf(v);
      }
      // read back as phase-2 A-frags (k = n*32 + {0..15, 16..31})
      a2[n * 2 + 0] = *reinterpret_cast<const bf16x8*>(&hw[lcol * 40 + hi * 8]);
      a2[n * 2 + 1] = *reinterpret_cast<const bf16x8*>(&hw[lcol * 40 + 16 + hi * 8]);
    }
    __syncthreads();   // all waves done reading this half before overwrite
  }

  // stage w2 fragments (64 KB) into the same buffer
#pragma unroll
  for (int i = 0; i < 16; ++i) {
    int cc = i * 4 + w;
    int4 v = *reinterpret_cast<const int4*>(
        w2fragG + (size_t)cc * 512 + lane * 8);
    *reinterpret_cast<int4*>(&wfrag[cc * 512 + lane * 8]) = v;
  }
  __syncthreads();

  // ---- phase 2: jp=0 -> t2 cols (j=0,1); jp=1 -> out cols (j=2,3) ----
#pragma unroll
  for (int jp = 0; jp < 2; ++jp) {
    if (jp == 1 && !do_out) break;
    const int jA = jp * 2, jB = jp * 2 + 1;
    f32x16 aA = (f32x16)0.0f, aB = (f32x16)0.0f;
#pragma unroll
    for (int s = 0; s < 8; ++s) {
      bf16x8 c0A = *reinterpret_cast<const bf16x8*>(
          &wfrag[((jA * 16 + s * 2) * 64 + lane) * 8]);
      bf16x8 c1A = *reinterpret_cast<const bf16x8*>(
          &wfrag[((jA * 16 + s * 2 + 1) * 64 + lane) * 8]);
      bf16x8 c0B = *reinterpret_cast<const bf16x8*>(
          &wfrag[((jB * 16 + s * 2) * 64 + lane) * 8]);
      bf16x8 c1B = *reinterpret_cast<const bf16x8*>(
          &wfrag[((jB * 16 + s * 2 + 1) * 64 + lane) * 8]);
      aA = __builtin_amdgcn_mfma_f32_32x32x16_bf16(a2[s * 2], c0A, aA, 0, 0, 0);
      aB = __builtin_amdgcn_mfma_f32_32x32x16_bf16(a2[s * 2], c0B, aB, 0, 0, 0);
      aA = __builtin_amdgcn_mfma_f32_32x32x16_bf16(a2[s * 2 + 1], c1A, aA, 0, 0, 0);
      aB = __builtin_amdgcn_mfma_f32_32x32x16_bf16(a2[s * 2 + 1], c1B, aB, 0, 0, 0);
    }
    if (jp == 0) {
#pragma unroll
      for (int r = 0; r < 16; ++r) {
        int R = (r & 3) + 8 * (r >> 2) + 4 * hi;
        int rg = row0 + R;
        if (rg < CN1) {
          t2[(size_t)rg * 64 + lcol] = f2bf(aA[r]);
          t2[(size_t)rg * 64 + 32 + lcol] = f2bf(aB[r]);
        }
      }
    } else {
#pragma unroll
      for (int r = 0; r < 16; ++r) {
        int R = (r & 3) + 8 * (r >> 2) + 4 * hi;
        int rg = row0 + R;
        outp[(size_t)rg * 64 + lcol] = aA[r];
        outp[(size_t)rg * 64 + 32 + lcol] = aB[r];
      }
    }
  }
}

extern "C" void kernel_launch(void* const* d_in, const int* in_sizes, int n_in,
                              void* d_out, int out_size, void* d_ws, size_t ws_size,
                              hipStream_t stream) {
  const float* x    = (const float*)d_in[0];
  const int* src1   = (const int*)d_in[1];
  const int* dst1   = (const int*)d_in[2];
  const int* src2   = (const int*)d_in[3];
  const int* dst2   = (const int*)d_in[4];
  const float* W_l1 = (const float*)d_in[5];
  const float* b_l1 = (const float*)d_in[6];
  const float* W_r1 = (const float*)d_in[7];
  const float* W_l2 = (const float*)d_in[8];
  const float* b_l2 = (const float*)d_in[9];
  const float* W_r2 = (const float*)d_in[10];
  float* out = (float*)d_out;
  char* base = (char*)d_ws;

  // ---- workspace layout (bytes), ~111.5 MB ----
  uint16_t* x_bf  = (uint16_t*)base;                       // 51.2 MB
  uint16_t* t2_bf = (uint16_t*)(base + 51200000);          // 12.8 MB
  uint32_t* pairs1= (uint32_t*)(base + 64000000);          // 6.4 MB (E1*4)
  uint32_t* pairs2= (uint32_t*)(base + 70400000);          // 1.28 MB (E2*4)
  uint16_t* agg_bf= (uint16_t*)(base + 71680000);          // 25.6 MB
  int* deg1 = (int*)(base + 102400000);                    // 400 KB
  int* R1   = (int*)(base + 102800000);                    // 400 KB
  int* esrc1= (int*)(base + 103200000);                    // 6.4 MB
  int* deg2 = (int*)(base + 109600000);                    // 80 KB
  int* R2   = (int*)(base + 109680000);                    // 80 KB
  int* esrc2= (int*)(base + 109760000);                    // 1.28 MB
  int* H1   = (int*)(base + 111040000);                    // 200,704 B
  int* H2   = (int*)(base + 111240704);                    // 10,240 B
  char* misc = base + 111250944;
  int* T1  = (int*)(misc);
  int* Bb1 = (int*)(misc + 1024);
  int* T2  = (int*)(misc + 2048);
  int* Bb2 = (int*)(misc + 3072);
  int* part1 = (int*)(misc + 4096);
  int* part2 = (int*)(misc + 5120);
  uint16_t* wfragG  = (uint16_t*)(misc + 6144);            // 128 KB (frag order)
  uint16_t* w2fragG = wfragG + 65536;                      // 64 KB (frag order)

  if (ws_size < 112000000u) return;

  // ---- fused converts + csr_count ----
  cvt_count<<<25368, 256, 0, stream>>>(x, W_l1, W_r1, W_l2, W_r2, dst1, dst2,
                                       x_bf, wfragG, w2fragG, H1, H2);

  // ---- dual-layer CSR build ----
  csr_scan<<<NBK1 + NBK2, 256, 0, stream>>>(H1, H2, T1, T2);
  csr_base<<<2, 256, 0, stream>>>(T1, T2, Bb1, Bb2);
  csr_place<<<G1 + G2, 256, 0, stream>>>(src1, dst1, src2, dst2, H1, H2,
                                         Bb1, Bb2, pairs1, pairs2);
  csr_bdeg<<<NBK1 + NBK2, 256, 0, stream>>>(pairs1, pairs2, Bb1, Bb2, T1, T2,
                                            deg1, deg2);
  csr_scan_local<<<NBK1 + NBK2, 256, 0, stream>>>(deg1, deg2, R1, R2, part1, part2);
  csr_scan_part<<<2, 256, 0, stream>>>(part1, part2);
  csr_bplace<<<NBK1 + NBK2, 256, 0, stream>>>(pairs1, pairs2, Bb1, Bb2, T1, T2,
                                              R1, R2, part1, part2, esrc1, esrc2);

  // ---- gather1 -> mega -> fused gather2+finalize ----
  sage_gather1<<<(CN1 + 3) / 4, 256, 0, stream>>>(x_bf, esrc1, R1, part1, deg1, agg_bf);
  sage_mega<<<(CN1 + 127) / 128, 256, 0, stream>>>(
      agg_bf, x_bf, wfragG, w2fragG, b_l1, t2_bf, out);
  sage_gather2_fin<<<(CN2 + 7) / 8, 256, 0, stream>>>(
      t2_bf, esrc2, R2, part2, deg2, b_l2, out);
}